// Round 13
// baseline (108.730 us; speedup 1.0000x reference)
//
#include <hip/hip_runtime.h>
#include <math.h>

#define D_MODEL 1024
#define N_HEADS 16
#define N_PHASE 128
#define HEAD_DIM 64
#define B_SZ 2
#define L_SEQ 2048
#define QK_SCALE 0.35355339059327373f   // 1/sqrt(8)
#define LOG2E 1.4426950408889634f
#define LN_EPS 1e-5f
#define POS_COEF 0.07195578415606394f   // ln(10000)/128
#define INV_2PI 0.15915494309189535f

typedef __attribute__((ext_vector_type(8))) short bf16x8;
typedef __attribute__((ext_vector_type(4))) short s16x4;
typedef __attribute__((ext_vector_type(4))) float f32x4;

// ---------------------------------------------------------------- helpers
__device__ __forceinline__ float wave_reduce_sum(float v) {
#pragma unroll
  for (int off = 32; off > 0; off >>= 1) v += __shfl_xor(v, off);
  return v;
}
// f32 -> bf16 (RNE)
__device__ __forceinline__ unsigned short f2bf(float x) {
  unsigned u = __float_as_uint(x);
  u += 0x7fffu + ((u >> 16) & 1u);
  return (unsigned short)(u >> 16);
}
__device__ __forceinline__ void gload16(const short* g, short* l) {
  __builtin_amdgcn_global_load_lds(
      (const __attribute__((address_space(1))) void*)g,
      (__attribute__((address_space(3))) void*)l, 16, 0, 0);
}
// hw sin/cos with explicit range reduction (v_sin/v_cos take REVOLUTIONS,
// limited domain -> reduce to [-0.5, 0.5] rev with rndne first)
__device__ __forceinline__ void fast_sincos(float ang, float* s, float* c) {
  float rev = ang * INV_2PI;
  rev = rev - rintf(rev);
  *c = __builtin_amdgcn_cosf(rev);
  *s = __builtin_amdgcn_sinf(rev);
}

// ---------------------------------------------------------------- merged converts
#define NX4 ((B_SZ * L_SEQ * D_MODEL) / 4)
#define NWP4 ((N_PHASE * D_MODEL) / 4)
#define NW4 ((D_MODEL * D_MODEL) / 4)
__device__ __forceinline__ s16x4 cvt4(float4 v) {
  s16x4 o;
  o[0] = (short)f2bf(v.x);
  o[1] = (short)f2bf(v.y);
  o[2] = (short)f2bf(v.z);
  o[3] = (short)f2bf(v.w);
  return o;
}
__global__ __launch_bounds__(256) void cvtall_kernel(
    const float* __restrict__ x_real, const float* __restrict__ x_imag,
    const float* __restrict__ Wq, const float* __restrict__ Wk,
    const float* __restrict__ Wv, const float* __restrict__ Wo,
    short* __restrict__ xr_bf, short* __restrict__ xi_bf,
    short* __restrict__ Wq_bf, short* __restrict__ Wk_bf,
    short* __restrict__ Wv_bf, short* __restrict__ Wo_bf,
    float* __restrict__ outi) {
  const int i = blockIdx.x * 256 + threadIdx.x;
  if (i < NX4) {
    const float4 vi = ((const float4*)x_imag)[i];
    ((float4*)outi)[i] = vi;
    ((s16x4*)xi_bf)[i] = cvt4(vi);
    ((s16x4*)xr_bf)[i] = cvt4(((const float4*)x_real)[i]);
  } else if (i < NX4 + NWP4) {
    const int j = i - NX4;
    ((s16x4*)Wq_bf)[j] = cvt4(((const float4*)Wq)[j]);
    ((s16x4*)Wk_bf)[j] = cvt4(((const float4*)Wk)[j]);
  } else if (i < NX4 + NWP4 + NW4) {
    const int j = i - NX4 - NWP4;
    ((s16x4*)Wv_bf)[j] = cvt4(((const float4*)Wv)[j]);
    ((s16x4*)Wo_bf)[j] = cvt4(((const float4*)Wo)[j]);
  }
}

// ---------------------------------------------------------------- GEMM core (m97 128x128)
// 128x128 tile, BK=32, 4 waves (2x2), wave tile 64x64, frags af[4] x bfr[4].
// Involution chunk-XOR swizzle on the GLOBAL source (gload_lds dest linear)
// and the same XOR on the LDS read side: LDS[row][c] = global[row][c ^
// ((row>>1)&3)]; read at fc ^ ((fr>>1)&3) recovers global chunk fc.
__device__ __forceinline__ void gemm_core(const short* __restrict__ A,
                                          const short* __restrict__ Bm, int K,
                                          int mBase, int nBase,
                                          f32x4 acc[4][4], short* As,
                                          short* Bs) {
  const int tid = threadIdx.x;
  const int wv = tid >> 6, ln = tid & 63;
  const int wr = wv >> 1, wc = wv & 1;
  const int fr = ln & 15, fc = ln >> 4;
  const int cg = (ln & 3) ^ ((ln >> 3) & 3);  // swizzled source chunk
  const short* ga = A + (size_t)(mBase + wv * 16 + (ln >> 2)) * K + cg * 8;
  const short* gb = Bm + (size_t)(nBase + wv * 16 + (ln >> 2)) * K + cg * 8;
  short* la = As + wv * 512;
  short* lb = Bs + wv * 512;
  const int ra = (wr * 64 + fr) * 32 + (fc ^ ((fr >> 1) & 3)) * 8;
  const int rb = (wc * 64 + fr) * 32 + (fc ^ ((fr >> 1) & 3)) * 8;

  for (int k0 = 0; k0 < K; k0 += 32) {
    __syncthreads();
    gload16(ga + k0, la);
    gload16(ga + k0 + (size_t)64 * K, la + 64 * 32);
    gload16(gb + k0, lb);
    gload16(gb + k0 + (size_t)64 * K, lb + 64 * 32);
    __syncthreads();

    bf16x8 af[4], bfr[4];
#pragma unroll
    for (int mi = 0; mi < 4; ++mi) af[mi] = *(const bf16x8*)&As[ra + mi * 512];
#pragma unroll
    for (int ni = 0; ni < 4; ++ni) bfr[ni] = *(const bf16x8*)&Bs[rb + ni * 512];

#pragma unroll
    for (int mi = 0; mi < 4; ++mi)
#pragma unroll
      for (int ni = 0; ni < 4; ++ni)
        acc[mi][ni] = __builtin_amdgcn_mfma_f32_16x16x32_bf16(
            af[mi], bfr[ni], acc[mi][ni], 0, 0, 0);
  }
}

// ---------------------------------------------------------------- fused QKV projections
// grid (M/128, 10): y=0 -> Q phase (N=128), y=1 -> K phase, y in [2,10) -> V
__global__ __launch_bounds__(256) void qkv_kernel(
    const short* __restrict__ xi, const short* __restrict__ xr,
    const short* __restrict__ WqB, const short* __restrict__ WkB,
    const short* __restrict__ WvB, const float* __restrict__ bq,
    const float* __restrict__ bk, short* __restrict__ qf,
    short* __restrict__ kf, short* __restrict__ Vt) {
  __shared__ short As[128 * 32];
  __shared__ short Bs[128 * 32];
  const int y = blockIdx.y;
  const int mBase = blockIdx.x * 128;
  const short* A;
  const short* Bm;
  int nBase;
  if (y < 2) {
    A = xi;
    Bm = y ? WkB : WqB;
    nBase = 0;
  } else {
    A = xr;
    Bm = WvB;
    nBase = (y - 2) * 128;
  }

  f32x4 acc[4][4];
#pragma unroll
  for (int i = 0; i < 4; ++i)
#pragma unroll
    for (int j = 0; j < 4; ++j) acc[i][j] = (f32x4){0.f, 0.f, 0.f, 0.f};
  gemm_core(A, Bm, D_MODEL, mBase, nBase, acc, As, Bs);

  const int ln = threadIdx.x & 63, wv = threadIdx.x >> 6;
  const int wr = wv >> 1, wc = wv & 1;
  const int fr = ln & 15, fc = ln >> 4;

  if (y < 2) {
    const float* bias = y ? bk : bq;
    short* Cs = y ? kf : qf;
    // fold log2(e) into Q's scale so attention can use raw v_exp (2^x)
    const float fscale = y ? 1.0f : (QK_SCALE * LOG2E);
#pragma unroll
    for (int mi = 0; mi < 4; ++mi)
#pragma unroll
      for (int ni = 0; ni < 4; ++ni)
#pragma unroll
        for (int r = 0; r < 4; ++r) {
          const int m = mBase + wr * 64 + mi * 16 + fc * 4 + r;
          const int n = wc * 64 + ni * 16 + fr;
          const int b = m >> 11, l = m & (L_SEQ - 1);
          const float inv_freq = __expf(-(float)(n & ~1) * POS_COEF);
          const float ang = acc[mi][ni][r] + bias[n] + (float)l * inv_freq;
          float sv, cv;
          fast_sincos(ang, &sv, &cv);
          const int h = n >> 3, p = n & 7;
          const size_t base = ((size_t)((b << 4) + h) * L_SEQ + l) * 16;
          Cs[base + p] = (short)f2bf(cv * fscale);
          Cs[base + 8 + p] = (short)f2bf(sv * fscale);
        }
  } else {
    // Vt: PI-permuted j-rows (position [g1 g0 e2 e1 e0] holds row
    // [e2 g1 g0 e1 e0]) AND subtile-contiguous layout: each 16d x 32j
    // subtile is 1 KB contiguous, ordered [g][dlo][e] to match lane order,
    // so attention's V load is a fully-coalesced 1 KB wave read.
#pragma unroll
    for (int mi = 0; mi < 4; ++mi)
#pragma unroll
      for (int ni = 0; ni < 4; ++ni) {
        const int n = nBase + wc * 64 + ni * 16 + fr;
        const int m = mBase + wr * 64 + mi * 16 + fc * 4;
        const int b = m >> 11, l = m & (L_SEQ - 1);
        const int t = (l >> 2) & 7;
        const int tp = ((t << 1) & 6) | (t >> 2);
        const int lpos = (l & ~31) | (tp << 2);
        const int h = n >> 6, d = n & 63;
        const int jc = lpos >> 5, jlo = lpos & 31;
        const int gg = jlo >> 3, ee = jlo & 7;
        s16x4 pk;
#pragma unroll
        for (int r = 0; r < 4; ++r) pk[r] = (short)f2bf(acc[mi][ni][r]);
        const size_t off = (size_t)((b << 4) + h) * 64 * L_SEQ +
                           (size_t)(jc * 4 + (d >> 4)) * 512 + gg * 128 +
                           (d & 15) * 8 + ee;
        *(s16x4*)&Vt[off] = pk;
      }
  }
}

// ---------------------------------------------------------------- O GEMM (+residual)
__global__ __launch_bounds__(256) void ogemm_kernel(
    const short* __restrict__ A, const short* __restrict__ Bm,
    const float* __restrict__ resid, float* __restrict__ Cf) {
  __shared__ short As[128 * 32];
  __shared__ short Bs[128 * 32];
  const int mBase = blockIdx.x * 128, nBase = blockIdx.y * 128;

  f32x4 acc[4][4];
#pragma unroll
  for (int i = 0; i < 4; ++i)
#pragma unroll
    for (int j = 0; j < 4; ++j) acc[i][j] = (f32x4){0.f, 0.f, 0.f, 0.f};
  gemm_core(A, Bm, D_MODEL, mBase, nBase, acc, As, Bs);

  const int ln = threadIdx.x & 63, wv = threadIdx.x >> 6;
  const int wr = wv >> 1, wc = wv & 1;
  const int fr = ln & 15, fc = ln >> 4;
#pragma unroll
  for (int mi = 0; mi < 4; ++mi)
#pragma unroll
    for (int ni = 0; ni < 4; ++ni)
#pragma unroll
      for (int r = 0; r < 4; ++r) {
        const int m = mBase + wr * 64 + mi * 16 + fc * 4 + r;
        const int n = nBase + wc * 64 + ni * 16 + fr;
        const size_t idx = (size_t)m * D_MODEL + n;
        Cf[idx] = acc[mi][ni][r] + resid[idx];
      }
}

// ---------------------------------------------------------------- MFMA attention
// Intra-block flash-split over j: grid (B*H, 128), block = one 16-row q-group
// (qg = 127 - y, longest-first), 4 waves; wave w does tiles t = w, w+4, ...
// with private partial o/lsum (bounded scores -> pure-sum combine), LDS
// combine at the end. V loads are 1 KB fully-coalesced wave reads from the
// subtile-contiguous Vt. Scores arrive pre-scaled by log2e -> exp2f = raw
// v_exp_f32 (no per-element pre-multiply).
__global__ __launch_bounds__(256) void attn_mfma_kernel(
    const short* __restrict__ qf, const short* __restrict__ kf,
    const short* __restrict__ Vt, short* __restrict__ ao) {
  const int bh = blockIdx.x;
  const int qg = 127 - (int)blockIdx.y;  // longest blocks dispatch first
  const int tid = threadIdx.x;
  const int w = tid >> 6;
  const int lane = tid & 63;
  const int g = lane >> 4;
  const int q16 = lane & 15;
  const int qglob = qg * 16 + q16;
  const int ntiles = (qg >> 2) + 1;

  __shared__ float ol[4][16][68];  // stride 68: 2-way bank aliasing only
  __shared__ float ll[4][16];

  const short* qf_h = qf + (size_t)bh * L_SEQ * 16;
  const short* kf_h = kf + (size_t)bh * L_SEQ * 16;
  const short* Vt_h = Vt + (size_t)bh * 64 * L_SEQ;
  const int b = bh >> 4, h = bh & 15;

  bf16x8 qfrag = {0, 0, 0, 0, 0, 0, 0, 0};
  if (g < 2) qfrag = *(const bf16x8*)(qf_h + (size_t)qglob * 16 + g * 8);

  f32x4 o[4];
#pragma unroll
  for (int dc = 0; dc < 4; ++dc) o[dc] = (f32x4){0.f, 0.f, 0.f, 0.f};
  float lsum = 0.f;

#pragma unroll 1
  for (int t = w; t < ntiles; t += 4) {
    const int j0 = t << 6;

    // V for this tile: subtile (2t+c)*4+dc, fully-coalesced 1 KB reads
    bf16x8 vf0[4], vf1[4];
#pragma unroll
    for (int dc = 0; dc < 4; ++dc)
      vf0[dc] = *(const bf16x8*)(Vt_h + ((size_t)((2 * t) * 4 + dc) << 9) +
                                 lane * 8);

    // K fragments for this tile
    bf16x8 kfr[4];
#pragma unroll
    for (int jt = 0; jt < 4; ++jt) {
      kfr[jt] = (bf16x8){0, 0, 0, 0, 0, 0, 0, 0};
      if (g < 2)
        kfr[jt] =
            *(const bf16x8*)(kf_h + (size_t)(j0 + jt * 16 + q16) * 16 + g * 8);
    }

    // QK^T (swapped): lane holds q=q16, j = j0 + jt*16 + g*4 + r
    f32x4 s[4];
#pragma unroll
    for (int jt = 0; jt < 4; ++jt)
      s[jt] = __builtin_amdgcn_mfma_f32_16x16x32_bf16(
          kfr[jt], qfrag, (f32x4){0.f, 0.f, 0.f, 0.f}, 0, 0, 0);

#pragma unroll
    for (int dc = 0; dc < 4; ++dc)
      vf1[dc] = *(const bf16x8*)(Vt_h + ((size_t)((2 * t + 1) * 4 + dc) << 9) +
                                 lane * 8);

    // causal mask (diagonal tile only)
    if (t == ntiles - 1) {
#pragma unroll
      for (int jt = 0; jt < 4; ++jt)
#pragma unroll
        for (int r = 0; r < 4; ++r)
          if (j0 + jt * 16 + g * 4 + r > qglob) s[jt][r] = -INFINITY;
    }

    // 2^s (scores pre-scaled by log2e) + per-lane partial sum
    float ex[4][4];
#pragma unroll
    for (int jt = 0; jt < 4; ++jt)
#pragma unroll
      for (int r = 0; r < 4; ++r) {
        ex[jt][r] = exp2f(s[jt][r]);
        lsum += ex[jt][r];
      }

    // PV: B-frag slot e -> (jt = 2c + (e>>2), r = e&3), all lane-local
#pragma unroll
    for (int c = 0; c < 2; ++c) {
      union {
        unsigned u[4];
        bf16x8 v;
      } pb;
#pragma unroll
      for (int hw = 0; hw < 2; ++hw) {
        pb.u[hw * 2 + 0] = (unsigned)f2bf(ex[2 * c + hw][0]) |
                           ((unsigned)f2bf(ex[2 * c + hw][1]) << 16);
        pb.u[hw * 2 + 1] = (unsigned)f2bf(ex[2 * c + hw][2]) |
                           ((unsigned)f2bf(ex[2 * c + hw][3]) << 16);
      }
      const bf16x8* vfc = c ? vf1 : vf0;
#pragma unroll
      for (int dc = 0; dc < 4; ++dc)
        o[dc] = __builtin_amdgcn_mfma_f32_16x16x32_bf16(vfc[dc], pb.v, o[dc],
                                                        0, 0, 0);
    }
  }

  // ---- combine the 4 waves' partials via LDS
  lsum += __shfl_xor(lsum, 16);
  lsum += __shfl_xor(lsum, 32);
  if (g == 0) ll[w][q16] = lsum;
#pragma unroll
  for (int dc = 0; dc < 4; ++dc)
    *(f32x4*)&ol[w][q16][dc * 16 + g * 4] = o[dc];
  __syncthreads();

  // wave w normalizes d-range [w*16, w*16+16)
  const float lt = (ll[0][q16] + ll[1][q16]) + (ll[2][q16] + ll[3][q16]);
  const float inv = 1.f / lt;
  const int d0 = w * 16 + g * 4;
  s16x4 pk;
#pragma unroll
  for (int r = 0; r < 4; ++r) {
    const float v = ((ol[0][q16][d0 + r] + ol[1][q16][d0 + r]) +
                     (ol[2][q16][d0 + r] + ol[3][q16][d0 + r]));
    pk[r] = (short)f2bf(v * inv);
  }
  short* orow = ao + ((size_t)(b * L_SEQ + qglob)) * D_MODEL + h * 64;
  *(s16x4*)&orow[d0] = pk;
}

// ---------------------------------------------------------------- layernorm (in place)
__global__ __launch_bounds__(256) void ln_kernel(float* __restrict__ io,
                                                 const float* __restrict__ gamma,
                                                 const float* __restrict__ beta) {
  const int row = blockIdx.x;
  float* p = io + (size_t)row * D_MODEL;
  const int tid = threadIdx.x;
  float4 x = ((const float4*)p)[tid];
  float s = x.x + x.y + x.z + x.w;
  float sq = x.x * x.x + x.y * x.y + x.z * x.z + x.w * x.w;
  s = wave_reduce_sum(s);
  sq = wave_reduce_sum(sq);
  __shared__ float ss[4], ssq[4];
  const int w = tid >> 6, lane = tid & 63;
  if (lane == 0) {
    ss[w] = s;
    ssq[w] = sq;
  }
  __syncthreads();
  s = ss[0] + ss[1] + ss[2] + ss[3];
  sq = ssq[0] + ssq[1] + ssq[2] + ssq[3];
  const float mean = s * (1.f / D_MODEL);
  const float var = sq * (1.f / D_MODEL) - mean * mean;
  const float rstd = rsqrtf(var + LN_EPS);
  const float4 g = ((const float4*)gamma)[tid];
  const float4 bt = ((const float4*)beta)[tid];
  float4 y;
  y.x = (x.x - mean) * rstd * g.x + bt.x;
  y.y = (x.y - mean) * rstd * g.y + bt.y;
  y.z = (x.z - mean) * rstd * g.z + bt.z;
  y.w = (x.w - mean) * rstd * g.w + bt.w;
  ((float4*)p)[tid] = y;
}

// ---------------------------------------------------------------- launch
extern "C" void kernel_launch(void* const* d_in, const int* in_sizes, int n_in,
                              void* d_out, int out_size, void* d_ws,
                              size_t ws_size, hipStream_t stream) {
  const float* x_real = (const float*)d_in[0];
  const float* x_imag = (const float*)d_in[1];
  const float* Wq = (const float*)d_in[2];
  const float* bq = (const float*)d_in[3];
  const float* Wk = (const float*)d_in[4];
  const float* bk = (const float*)d_in[5];
  const float* Wv = (const float*)d_in[6];
  const float* Wo = (const float*)d_in[7];
  const float* gamma = (const float*)d_in[8];
  const float* beta = (const float*)d_in[9];

  const size_t n_x = (size_t)B_SZ * L_SEQ * D_MODEL;        // 4M
  const size_t n_w = (size_t)D_MODEL * D_MODEL;             // 1M
  const size_t n_wp = (size_t)N_PHASE * D_MODEL;            // 128K
  const size_t n_qf = (size_t)B_SZ * N_HEADS * L_SEQ * 16;  // 1M

  short* xi_bf = (short*)d_ws;
  short* xr_bf = xi_bf + n_x;  // later reused as ao_bf
  short* Wq_bf = xr_bf + n_x;
  short* Wk_bf = Wq_bf + n_wp;
  short* Wv_bf = Wk_bf + n_wp;
  short* Wo_bf = Wv_bf + n_w;
  short* qf = Wo_bf + n_w;
  short* kf = qf + n_qf;
  short* Vt = kf + n_qf;  // 4M shorts
  short* ao_bf = xr_bf;   // alias: x_real bf16 dead after V GEMM

  float* outr = (float*)d_out;
  float* outi = outr + n_x;

  const dim3 blk(256);
  const int M = B_SZ * L_SEQ;  // 4096

  const int cvt_blocks = (NX4 + NWP4 + NW4 + 255) / 256;
  cvtall_kernel<<<dim3(cvt_blocks), blk, 0, stream>>>(
      x_real, x_imag, Wq, Wk, Wv, Wo, xr_bf, xi_bf, Wq_bf, Wk_bf, Wv_bf,
      Wo_bf, outi);

  qkv_kernel<<<dim3(M / 128, 10), blk, 0, stream>>>(
      xi_bf, xr_bf, Wq_bf, Wk_bf, Wv_bf, bq, bk, qf, kf, Vt);
  attn_mfma_kernel<<<dim3(B_SZ * N_HEADS, 128), blk, 0, stream>>>(qf, kf, Vt,
                                                                  ao_bf);
  ogemm_kernel<<<dim3(M / 128, D_MODEL / 128), blk, 0, stream>>>(
      ao_bf, Wo_bf, x_real, outr);
  ln_kernel<<<dim3(M), blk, 0, stream>>>(outr, gamma, beta);
}

// Round 14
// 98.233 us; speedup vs baseline: 1.1069x; 1.1069x over previous
//
#include <hip/hip_runtime.h>
#include <math.h>

#define D_MODEL 1024
#define N_HEADS 16
#define N_PHASE 128
#define HEAD_DIM 64
#define B_SZ 2
#define L_SEQ 2048
#define QK_SCALE 0.35355339059327373f   // 1/sqrt(8)
#define LN_EPS 1e-5f
#define POS_COEF 0.07195578415606394f   // ln(10000)/128
#define INV_2PI 0.15915494309189535f

typedef __attribute__((ext_vector_type(8))) short bf16x8;
typedef __attribute__((ext_vector_type(4))) short s16x4;
typedef __attribute__((ext_vector_type(4))) float f32x4;

// ---------------------------------------------------------------- helpers
__device__ __forceinline__ float wave_reduce_sum(float v) {
#pragma unroll
  for (int off = 32; off > 0; off >>= 1) v += __shfl_xor(v, off);
  return v;
}
// f32 -> bf16 (RNE)
__device__ __forceinline__ unsigned short f2bf(float x) {
  unsigned u = __float_as_uint(x);
  u += 0x7fffu + ((u >> 16) & 1u);
  return (unsigned short)(u >> 16);
}
__device__ __forceinline__ void gload16(const short* g, short* l) {
  __builtin_amdgcn_global_load_lds(
      (const __attribute__((address_space(1))) void*)g,
      (__attribute__((address_space(3))) void*)l, 16, 0, 0);
}
// hw sin/cos with explicit range reduction (v_sin/v_cos take REVOLUTIONS,
// limited domain -> reduce to [-0.5, 0.5] rev with rndne first)
__device__ __forceinline__ void fast_sincos(float ang, float* s, float* c) {
  float rev = ang * INV_2PI;
  rev = rev - rintf(rev);
  *c = __builtin_amdgcn_cosf(rev);
  *s = __builtin_amdgcn_sinf(rev);
}

// ---------------------------------------------------------------- merged converts
#define NX4 ((B_SZ * L_SEQ * D_MODEL) / 4)
#define NWP4 ((N_PHASE * D_MODEL) / 4)
#define NW4 ((D_MODEL * D_MODEL) / 4)
__device__ __forceinline__ s16x4 cvt4(float4 v) {
  s16x4 o;
  o[0] = (short)f2bf(v.x);
  o[1] = (short)f2bf(v.y);
  o[2] = (short)f2bf(v.z);
  o[3] = (short)f2bf(v.w);
  return o;
}
__global__ __launch_bounds__(256) void cvtall_kernel(
    const float* __restrict__ x_real, const float* __restrict__ x_imag,
    const float* __restrict__ Wq, const float* __restrict__ Wk,
    const float* __restrict__ Wv, const float* __restrict__ Wo,
    short* __restrict__ xr_bf, short* __restrict__ xi_bf,
    short* __restrict__ Wq_bf, short* __restrict__ Wk_bf,
    short* __restrict__ Wv_bf, short* __restrict__ Wo_bf,
    float* __restrict__ outi) {
  const int i = blockIdx.x * 256 + threadIdx.x;
  if (i < NX4) {
    const float4 vi = ((const float4*)x_imag)[i];
    ((float4*)outi)[i] = vi;
    ((s16x4*)xi_bf)[i] = cvt4(vi);
    ((s16x4*)xr_bf)[i] = cvt4(((const float4*)x_real)[i]);
  } else if (i < NX4 + NWP4) {
    const int j = i - NX4;
    ((s16x4*)Wq_bf)[j] = cvt4(((const float4*)Wq)[j]);
    ((s16x4*)Wk_bf)[j] = cvt4(((const float4*)Wk)[j]);
  } else if (i < NX4 + NWP4 + NW4) {
    const int j = i - NX4 - NWP4;
    ((s16x4*)Wv_bf)[j] = cvt4(((const float4*)Wv)[j]);
    ((s16x4*)Wo_bf)[j] = cvt4(((const float4*)Wo)[j]);
  }
}

// ---------------------------------------------------------------- GEMM core
// 128x64 tile, BK=32, 4 waves (2x2). Wave tile 64x32, frags af[4] x bfr[2].
// LDS chunk-XOR swizzle (involution) applied on the GLOBAL source
// (gload_lds dest is linear) and on the LDS read side.
__device__ __forceinline__ void gemm_core(const short* __restrict__ A,
                                          const short* __restrict__ Bm, int K,
                                          int mBase, int nBase,
                                          f32x4 acc[4][2], short* As,
                                          short* Bs) {
  const int tid = threadIdx.x;
  const int wv = tid >> 6, ln = tid & 63;
  const int wr = wv >> 1, wc = wv & 1;
  const int fr = ln & 15, fc = ln >> 4;
  const int cg = (ln & 3) ^ ((ln >> 3) & 3);  // swizzled source chunk
  const short* ga = A + (size_t)(mBase + wv * 16 + (ln >> 2)) * K + cg * 8;
  const short* gb = Bm + (size_t)(nBase + wv * 16 + (ln >> 2)) * K + cg * 8;
  short* la = As + wv * 512;
  short* lb = Bs + wv * 512;
  const int ra = (wr * 64 + fr) * 32 + (fc ^ ((fr >> 1) & 3)) * 8;
  const int rb = (wc * 32 + fr) * 32 + (fc ^ ((fr >> 1) & 3)) * 8;

  for (int k0 = 0; k0 < K; k0 += 32) {
    __syncthreads();
    gload16(ga + k0, la);
    gload16(ga + k0 + (size_t)64 * K, la + 64 * 32);
    gload16(gb + k0, lb);
    __syncthreads();

    bf16x8 af[4], bfr[2];
#pragma unroll
    for (int mi = 0; mi < 4; ++mi) af[mi] = *(const bf16x8*)&As[ra + mi * 512];
#pragma unroll
    for (int ni = 0; ni < 2; ++ni) bfr[ni] = *(const bf16x8*)&Bs[rb + ni * 512];

#pragma unroll
    for (int mi = 0; mi < 4; ++mi)
#pragma unroll
      for (int ni = 0; ni < 2; ++ni)
        acc[mi][ni] = __builtin_amdgcn_mfma_f32_16x16x32_bf16(
            af[mi], bfr[ni], acc[mi][ni], 0, 0, 0);
  }
}

// ---------------------------------------------------------------- fused QKV projections
// grid (M/128, 20): y in [0,2) -> Q phase, [2,4) -> K phase, [4,20) -> V GEMM
__global__ __launch_bounds__(256) void qkv_kernel(
    const short* __restrict__ xi, const short* __restrict__ xr,
    const short* __restrict__ WqB, const short* __restrict__ WkB,
    const short* __restrict__ WvB, const float* __restrict__ bq,
    const float* __restrict__ bk, short* __restrict__ qf,
    short* __restrict__ kf, short* __restrict__ Vt) {
  __shared__ short As[128 * 32];
  __shared__ short Bs[64 * 32];
  const int y = blockIdx.y;
  const int mBase = blockIdx.x * 128;
  const short* A;
  const short* Bm;
  int nBase;
  if (y < 4) {
    A = xi;
    Bm = (y < 2) ? WqB : WkB;
    nBase = (y & 1) * 64;
  } else {
    A = xr;
    Bm = WvB;
    nBase = (y - 4) * 64;
  }

  f32x4 acc[4][2];
#pragma unroll
  for (int i = 0; i < 4; ++i)
#pragma unroll
    for (int j = 0; j < 2; ++j) acc[i][j] = (f32x4){0.f, 0.f, 0.f, 0.f};
  gemm_core(A, Bm, D_MODEL, mBase, nBase, acc, As, Bs);

  const int ln = threadIdx.x & 63, wv = threadIdx.x >> 6;
  const int wr = wv >> 1, wc = wv & 1;
  const int fr = ln & 15, fc = ln >> 4;

  if (y < 4) {
    const float* bias = (y < 2) ? bq : bk;
    short* Cs = (y < 2) ? qf : kf;
    const float fscale = (y < 2) ? QK_SCALE : 1.0f;
#pragma unroll
    for (int mi = 0; mi < 4; ++mi)
#pragma unroll
      for (int ni = 0; ni < 2; ++ni)
#pragma unroll
        for (int r = 0; r < 4; ++r) {
          const int m = mBase + wr * 64 + mi * 16 + fc * 4 + r;
          const int n = nBase + wc * 32 + ni * 16 + fr;
          const int b = m >> 11, l = m & (L_SEQ - 1);
          const float inv_freq = __expf(-(float)(n & ~1) * POS_COEF);
          const float ang = acc[mi][ni][r] + bias[n] + (float)l * inv_freq;
          float sv, cv;
          fast_sincos(ang, &sv, &cv);
          const int h = n >> 3, p = n & 7;
          const size_t base = ((size_t)((b << 4) + h) * L_SEQ + l) * 16;
          Cs[base + p] = (short)f2bf(cv * fscale);
          Cs[base + 8 + p] = (short)f2bf(sv * fscale);
        }
  } else {
    // Vt: PI-permuted j-rows (position [g1 g0 e2 e1 e0] holds row
    // [e2 g1 g0 e1 e0]) AND subtile-contiguous layout: each 16d x 32j
    // subtile is 1 KB contiguous, ordered [g][dlo][e] to match lane order,
    // so attention's V load is a fully-coalesced 1 KB wave read.
#pragma unroll
    for (int mi = 0; mi < 4; ++mi)
#pragma unroll
      for (int ni = 0; ni < 2; ++ni) {
        const int n = nBase + wc * 32 + ni * 16 + fr;
        const int m = mBase + wr * 64 + mi * 16 + fc * 4;
        const int b = m >> 11, l = m & (L_SEQ - 1);
        const int t = (l >> 2) & 7;
        const int tp = ((t << 1) & 6) | (t >> 2);
        const int lpos = (l & ~31) | (tp << 2);
        const int h = n >> 6, d = n & 63;
        const int jc = lpos >> 5, jlo = lpos & 31;
        const int gg = jlo >> 3, ee = jlo & 7;
        s16x4 pk;
#pragma unroll
        for (int r = 0; r < 4; ++r) pk[r] = (short)f2bf(acc[mi][ni][r]);
        const size_t off = (size_t)((b << 4) + h) * 64 * L_SEQ +
                           (size_t)(jc * 4 + (d >> 4)) * 512 + gg * 128 +
                           (d & 15) * 8 + ee;
        *(s16x4*)&Vt[off] = pk;
      }
  }
}

// ---------------------------------------------------------------- O GEMM (+residual)
__global__ __launch_bounds__(256) void ogemm_kernel(
    const short* __restrict__ A, const short* __restrict__ Bm,
    const float* __restrict__ resid, float* __restrict__ Cf) {
  __shared__ short As[128 * 32];
  __shared__ short Bs[64 * 32];
  const int mBase = blockIdx.x * 128, nBase = blockIdx.y * 64;

  f32x4 acc[4][2];
#pragma unroll
  for (int i = 0; i < 4; ++i)
#pragma unroll
    for (int j = 0; j < 2; ++j) acc[i][j] = (f32x4){0.f, 0.f, 0.f, 0.f};
  gemm_core(A, Bm, D_MODEL, mBase, nBase, acc, As, Bs);

  const int ln = threadIdx.x & 63, wv = threadIdx.x >> 6;
  const int wr = wv >> 1, wc = wv & 1;
  const int fr = ln & 15, fc = ln >> 4;
#pragma unroll
  for (int mi = 0; mi < 4; ++mi)
#pragma unroll
    for (int ni = 0; ni < 2; ++ni)
#pragma unroll
      for (int r = 0; r < 4; ++r) {
        const int m = mBase + wr * 64 + mi * 16 + fc * 4 + r;
        const int n = nBase + wc * 32 + ni * 16 + fr;
        const size_t idx = (size_t)m * D_MODEL + n;
        Cf[idx] = acc[mi][ni][r] + resid[idx];
      }
}

// ---------------------------------------------------------------- MFMA attention
// Intra-block flash-split over j: grid (B*H, 128), block = one 16-row q-group
// (qg = 127 - y, longest-first), 4 waves; wave w does tiles t = w, w+4, ...
// with private partial o/lsum (bounded scores -> pure-sum combine), LDS
// combine at the end. V loads are 1 KB fully-coalesced wave reads from the
// subtile-contiguous Vt. P-pack uses v_cvt_pk_bf16_f32 (8 ops/tile instead
// of ~72 manual-RNE ops) -- same RNE rounding, attacks the VALU bound.
__global__ __launch_bounds__(256) void attn_mfma_kernel(
    const short* __restrict__ qf, const short* __restrict__ kf,
    const short* __restrict__ Vt, short* __restrict__ ao) {
  const int bh = blockIdx.x;
  const int qg = 127 - (int)blockIdx.y;  // longest blocks dispatch first
  const int tid = threadIdx.x;
  const int w = tid >> 6;
  const int lane = tid & 63;
  const int g = lane >> 4;
  const int q16 = lane & 15;
  const int qglob = qg * 16 + q16;
  const int ntiles = (qg >> 2) + 1;

  __shared__ float ol[4][16][68];  // stride 68: 2-way bank aliasing only
  __shared__ float ll[4][16];

  const short* qf_h = qf + (size_t)bh * L_SEQ * 16;
  const short* kf_h = kf + (size_t)bh * L_SEQ * 16;
  const short* Vt_h = Vt + (size_t)bh * 64 * L_SEQ;
  const int b = bh >> 4, h = bh & 15;

  bf16x8 qfrag = {0, 0, 0, 0, 0, 0, 0, 0};
  if (g < 2) qfrag = *(const bf16x8*)(qf_h + (size_t)qglob * 16 + g * 8);

  f32x4 o[4];
#pragma unroll
  for (int dc = 0; dc < 4; ++dc) o[dc] = (f32x4){0.f, 0.f, 0.f, 0.f};
  float lsum = 0.f;

#pragma unroll 1
  for (int t = w; t < ntiles; t += 4) {
    const int j0 = t << 6;

    // V for this tile: subtile (2t+c)*4+dc, fully-coalesced 1 KB reads
    bf16x8 vf0[4], vf1[4];
#pragma unroll
    for (int dc = 0; dc < 4; ++dc)
      vf0[dc] = *(const bf16x8*)(Vt_h + ((size_t)((2 * t) * 4 + dc) << 9) +
                                 lane * 8);

    // K fragments for this tile
    bf16x8 kfr[4];
#pragma unroll
    for (int jt = 0; jt < 4; ++jt) {
      kfr[jt] = (bf16x8){0, 0, 0, 0, 0, 0, 0, 0};
      if (g < 2)
        kfr[jt] =
            *(const bf16x8*)(kf_h + (size_t)(j0 + jt * 16 + q16) * 16 + g * 8);
    }

    // QK^T (swapped): lane holds q=q16, j = j0 + jt*16 + g*4 + r
    f32x4 s[4];
#pragma unroll
    for (int jt = 0; jt < 4; ++jt)
      s[jt] = __builtin_amdgcn_mfma_f32_16x16x32_bf16(
          kfr[jt], qfrag, (f32x4){0.f, 0.f, 0.f, 0.f}, 0, 0, 0);

#pragma unroll
    for (int dc = 0; dc < 4; ++dc)
      vf1[dc] = *(const bf16x8*)(Vt_h + ((size_t)((2 * t + 1) * 4 + dc) << 9) +
                                 lane * 8);

    // causal mask (diagonal tile only)
    if (t == ntiles - 1) {
#pragma unroll
      for (int jt = 0; jt < 4; ++jt)
#pragma unroll
        for (int r = 0; r < 4; ++r)
          if (j0 + jt * 16 + g * 4 + r > qglob) s[jt][r] = -INFINITY;
    }

    // exp + per-lane partial sum (P stays in registers)
    float ex[4][4];
#pragma unroll
    for (int jt = 0; jt < 4; ++jt)
#pragma unroll
      for (int r = 0; r < 4; ++r) {
        ex[jt][r] = __expf(s[jt][r]);
        lsum += ex[jt][r];
      }

    // PV: B-frag slot e -> (jt = 2c + (e>>2), r = e&3), all lane-local.
    // Pack via v_cvt_pk_bf16_f32 (RNE, 2 f32 -> 1 dword of 2 bf16).
#pragma unroll
    for (int c = 0; c < 2; ++c) {
      union {
        unsigned u[4];
        bf16x8 v;
      } pb;
#pragma unroll
      for (int hw = 0; hw < 2; ++hw) {
        asm("v_cvt_pk_bf16_f32 %0, %1, %2"
            : "=v"(pb.u[hw * 2 + 0])
            : "v"(ex[2 * c + hw][0]), "v"(ex[2 * c + hw][1]));
        asm("v_cvt_pk_bf16_f32 %0, %1, %2"
            : "=v"(pb.u[hw * 2 + 1])
            : "v"(ex[2 * c + hw][2]), "v"(ex[2 * c + hw][3]));
      }
      const bf16x8* vfc = c ? vf1 : vf0;
#pragma unroll
      for (int dc = 0; dc < 4; ++dc)
        o[dc] = __builtin_amdgcn_mfma_f32_16x16x32_bf16(vfc[dc], pb.v, o[dc],
                                                        0, 0, 0);
    }
  }

  // ---- combine the 4 waves' partials via LDS
  lsum += __shfl_xor(lsum, 16);
  lsum += __shfl_xor(lsum, 32);
  if (g == 0) ll[w][q16] = lsum;
#pragma unroll
  for (int dc = 0; dc < 4; ++dc)
    *(f32x4*)&ol[w][q16][dc * 16 + g * 4] = o[dc];
  __syncthreads();

  // wave w normalizes d-range [w*16, w*16+16)
  const float lt = (ll[0][q16] + ll[1][q16]) + (ll[2][q16] + ll[3][q16]);
  const float inv = 1.f / lt;
  const int d0 = w * 16 + g * 4;
  s16x4 pk;
#pragma unroll
  for (int r = 0; r < 4; ++r) {
    const float v = ((ol[0][q16][d0 + r] + ol[1][q16][d0 + r]) +
                     (ol[2][q16][d0 + r] + ol[3][q16][d0 + r]));
    pk[r] = (short)f2bf(v * inv);
  }
  short* orow = ao + ((size_t)(b * L_SEQ + qglob)) * D_MODEL + h * 64;
  *(s16x4*)&orow[d0] = pk;
}

// ---------------------------------------------------------------- layernorm (in place)
__global__ __launch_bounds__(256) void ln_kernel(float* __restrict__ io,
                                                 const float* __restrict__ gamma,
                                                 const float* __restrict__ beta) {
  const int row = blockIdx.x;
  float* p = io + (size_t)row * D_MODEL;
  const int tid = threadIdx.x;
  float4 x = ((const float4*)p)[tid];
  float s = x.x + x.y + x.z + x.w;
  float sq = x.x * x.x + x.y * x.y + x.z * x.z + x.w * x.w;
  s = wave_reduce_sum(s);
  sq = wave_reduce_sum(sq);
  __shared__ float ss[4], ssq[4];
  const int w = tid >> 6, lane = tid & 63;
  if (lane == 0) {
    ss[w] = s;
    ssq[w] = sq;
  }
  __syncthreads();
  s = ss[0] + ss[1] + ss[2] + ss[3];
  sq = ssq[0] + ssq[1] + ssq[2] + ssq[3];
  const float mean = s * (1.f / D_MODEL);
  const float var = sq * (1.f / D_MODEL) - mean * mean;
  const float rstd = rsqrtf(var + LN_EPS);
  const float4 g = ((const float4*)gamma)[tid];
  const float4 bt = ((const float4*)beta)[tid];
  float4 y;
  y.x = (x.x - mean) * rstd * g.x + bt.x;
  y.y = (x.y - mean) * rstd * g.y + bt.y;
  y.z = (x.z - mean) * rstd * g.z + bt.z;
  y.w = (x.w - mean) * rstd * g.w + bt.w;
  ((float4*)p)[tid] = y;
}

// ---------------------------------------------------------------- launch
extern "C" void kernel_launch(void* const* d_in, const int* in_sizes, int n_in,
                              void* d_out, int out_size, void* d_ws,
                              size_t ws_size, hipStream_t stream) {
  const float* x_real = (const float*)d_in[0];
  const float* x_imag = (const float*)d_in[1];
  const float* Wq = (const float*)d_in[2];
  const float* bq = (const float*)d_in[3];
  const float* Wk = (const float*)d_in[4];
  const float* bk = (const float*)d_in[5];
  const float* Wv = (const float*)d_in[6];
  const float* Wo = (const float*)d_in[7];
  const float* gamma = (const float*)d_in[8];
  const float* beta = (const float*)d_in[9];

  const size_t n_x = (size_t)B_SZ * L_SEQ * D_MODEL;        // 4M
  const size_t n_w = (size_t)D_MODEL * D_MODEL;             // 1M
  const size_t n_wp = (size_t)N_PHASE * D_MODEL;            // 128K
  const size_t n_qf = (size_t)B_SZ * N_HEADS * L_SEQ * 16;  // 1M

  short* xi_bf = (short*)d_ws;
  short* xr_bf = xi_bf + n_x;  // later reused as ao_bf
  short* Wq_bf = xr_bf + n_x;
  short* Wk_bf = Wq_bf + n_wp;
  short* Wv_bf = Wk_bf + n_wp;
  short* Wo_bf = Wv_bf + n_w;
  short* qf = Wo_bf + n_w;
  short* kf = qf + n_qf;
  short* Vt = kf + n_qf;  // 4M shorts
  short* ao_bf = xr_bf;   // alias: x_real bf16 dead after V GEMM

  float* outr = (float*)d_out;
  float* outi = outr + n_x;

  const dim3 blk(256);
  const int M = B_SZ * L_SEQ;  // 4096

  const int cvt_blocks = (NX4 + NWP4 + NW4 + 255) / 256;
  cvtall_kernel<<<dim3(cvt_blocks), blk, 0, stream>>>(
      x_real, x_imag, Wq, Wk, Wv, Wo, xr_bf, xi_bf, Wq_bf, Wk_bf, Wv_bf,
      Wo_bf, outi);

  qkv_kernel<<<dim3(M / 128, 20), blk, 0, stream>>>(
      xi_bf, xr_bf, Wq_bf, Wk_bf, Wv_bf, bq, bk, qf, kf, Vt);
  attn_mfma_kernel<<<dim3(B_SZ * N_HEADS, 128), blk, 0, stream>>>(qf, kf, Vt,
                                                                  ao_bf);
  ogemm_kernel<<<dim3(M / 128, D_MODEL / 64), blk, 0, stream>>>(
      ao_bf, Wo_bf, x_real, outr);
  ln_kernel<<<dim3(M), blk, 0, stream>>>(outr, gamma, beta);
}

// Round 15
// 95.826 us; speedup vs baseline: 1.1347x; 1.0251x over previous
//
#include <hip/hip_runtime.h>
#include <math.h>

#define D_MODEL 1024
#define N_HEADS 16
#define N_PHASE 128
#define HEAD_DIM 64
#define B_SZ 2
#define L_SEQ 2048
#define QK_SCALE 0.35355339059327373f   // 1/sqrt(8)
#define LN_EPS 1e-5f
#define POS_COEF 0.07195578415606394f   // ln(10000)/128
#define INV_2PI 0.15915494309189535f

typedef __attribute__((ext_vector_type(8))) short bf16x8;
typedef __attribute__((ext_vector_type(4))) short s16x4;
typedef __attribute__((ext_vector_type(4))) float f32x4;

// ---------------------------------------------------------------- helpers
__device__ __forceinline__ float wave_reduce_sum(float v) {
#pragma unroll
  for (int off = 32; off > 0; off >>= 1) v += __shfl_xor(v, off);
  return v;
}
// f32 -> bf16 (RNE)
__device__ __forceinline__ unsigned short f2bf(float x) {
  unsigned u = __float_as_uint(x);
  u += 0x7fffu + ((u >> 16) & 1u);
  return (unsigned short)(u >> 16);
}
__device__ __forceinline__ void gload16(const short* g, short* l) {
  __builtin_amdgcn_global_load_lds(
      (const __attribute__((address_space(1))) void*)g,
      (__attribute__((address_space(3))) void*)l, 16, 0, 0);
}
// hw sin/cos with explicit range reduction (v_sin/v_cos take REVOLUTIONS,
// limited domain -> reduce to [-0.5, 0.5] rev with rndne first)
__device__ __forceinline__ void fast_sincos(float ang, float* s, float* c) {
  float rev = ang * INV_2PI;
  rev = rev - rintf(rev);
  *c = __builtin_amdgcn_cosf(rev);
  *s = __builtin_amdgcn_sinf(rev);
}

// ---------------------------------------------------------------- merged converts
#define NX4 ((B_SZ * L_SEQ * D_MODEL) / 4)
#define NWP4 ((N_PHASE * D_MODEL) / 4)
#define NW4 ((D_MODEL * D_MODEL) / 4)
__device__ __forceinline__ s16x4 cvt4(float4 v) {
  s16x4 o;
  o[0] = (short)f2bf(v.x);
  o[1] = (short)f2bf(v.y);
  o[2] = (short)f2bf(v.z);
  o[3] = (short)f2bf(v.w);
  return o;
}
__global__ __launch_bounds__(256) void cvtall_kernel(
    const float* __restrict__ x_real, const float* __restrict__ x_imag,
    const float* __restrict__ Wq, const float* __restrict__ Wk,
    const float* __restrict__ Wv, const float* __restrict__ Wo,
    short* __restrict__ xr_bf, short* __restrict__ xi_bf,
    short* __restrict__ Wq_bf, short* __restrict__ Wk_bf,
    short* __restrict__ Wv_bf, short* __restrict__ Wo_bf,
    float* __restrict__ outi) {
  const int i = blockIdx.x * 256 + threadIdx.x;
  if (i < NX4) {
    const float4 vi = ((const float4*)x_imag)[i];
    ((float4*)outi)[i] = vi;
    ((s16x4*)xi_bf)[i] = cvt4(vi);
    ((s16x4*)xr_bf)[i] = cvt4(((const float4*)x_real)[i]);
  } else if (i < NX4 + NWP4) {
    const int j = i - NX4;
    ((s16x4*)Wq_bf)[j] = cvt4(((const float4*)Wq)[j]);
    ((s16x4*)Wk_bf)[j] = cvt4(((const float4*)Wk)[j]);
  } else if (i < NX4 + NWP4 + NW4) {
    const int j = i - NX4 - NWP4;
    ((s16x4*)Wv_bf)[j] = cvt4(((const float4*)Wv)[j]);
    ((s16x4*)Wo_bf)[j] = cvt4(((const float4*)Wo)[j]);
  }
}

// ---------------------------------------------------------------- GEMM core
// 128x64 tile, BK=64 (2 barriers per 64-wide K step -> half the drains of
// BK=32). Staging: 8 rows x 8 chunks of 8 shorts per gload16; involution
// swizzle chunk ^= (row&7) on the GLOBAL source (gload_lds dest is linear);
// read side uses p = (kk*4+fc) ^ (fr&7) -> 2-way bank spread (free).
__device__ __forceinline__ void gemm_core(const short* __restrict__ A,
                                          const short* __restrict__ Bm, int K,
                                          int mBase, int nBase,
                                          f32x4 acc[4][2], short* As,
                                          short* Bs) {
  const int tid = threadIdx.x;
  const int wv = tid >> 6, ln = tid & 63;
  const int wr = wv >> 1, wc = wv & 1;
  const int fr = ln & 15, fc = ln >> 4;
  const int row8 = ln >> 3;              // 0..7 within an 8-row stripe
  const int cg = (ln & 7) ^ row8;        // swizzled global source chunk
  const short* ga = A + (size_t)(mBase + wv * 32 + row8) * K + cg * 8;
  const short* gb = Bm + (size_t)(nBase + wv * 16 + row8) * K + cg * 8;
  short* la = As + wv * 2048;            // 32 rows x 64 cols per wave
  short* lb = Bs + wv * 1024;            // 16 rows x 64 cols per wave
  const int swz = fr & 7;

  for (int k0 = 0; k0 < K; k0 += 64) {
    __syncthreads();
#pragma unroll
    for (int i = 0; i < 4; ++i)
      gload16(ga + k0 + (size_t)(8 * i) * K, la + i * 512);
#pragma unroll
    for (int i = 0; i < 2; ++i)
      gload16(gb + k0 + (size_t)(8 * i) * K, lb + i * 512);
    __syncthreads();

    bf16x8 af[2][4], bfr[2][2];
#pragma unroll
    for (int kk = 0; kk < 2; ++kk) {
      const int pc = ((kk * 4 + fc) ^ swz) * 8;
#pragma unroll
      for (int mi = 0; mi < 4; ++mi)
        af[kk][mi] =
            *(const bf16x8*)&As[(wr * 64 + mi * 16 + fr) * 64 + pc];
#pragma unroll
      for (int ni = 0; ni < 2; ++ni)
        bfr[kk][ni] =
            *(const bf16x8*)&Bs[(wc * 32 + ni * 16 + fr) * 64 + pc];
    }
#pragma unroll
    for (int kk = 0; kk < 2; ++kk)
#pragma unroll
      for (int mi = 0; mi < 4; ++mi)
#pragma unroll
        for (int ni = 0; ni < 2; ++ni)
          acc[mi][ni] = __builtin_amdgcn_mfma_f32_16x16x32_bf16(
              af[kk][mi], bfr[kk][ni], acc[mi][ni], 0, 0, 0);
  }
}

// ---------------------------------------------------------------- fused QKV projections
// grid (M/128, 20): y in [0,2) -> Q phase, [2,4) -> K phase, [4,20) -> V GEMM
__global__ __launch_bounds__(256) void qkv_kernel(
    const short* __restrict__ xi, const short* __restrict__ xr,
    const short* __restrict__ WqB, const short* __restrict__ WkB,
    const short* __restrict__ WvB, const float* __restrict__ bq,
    const float* __restrict__ bk, short* __restrict__ qf,
    short* __restrict__ kf, short* __restrict__ Vt) {
  __shared__ short As[128 * 64];
  __shared__ short Bs[64 * 64];
  const int y = blockIdx.y;
  const int mBase = blockIdx.x * 128;
  const short* A;
  const short* Bm;
  int nBase;
  if (y < 4) {
    A = xi;
    Bm = (y < 2) ? WqB : WkB;
    nBase = (y & 1) * 64;
  } else {
    A = xr;
    Bm = WvB;
    nBase = (y - 4) * 64;
  }

  f32x4 acc[4][2];
#pragma unroll
  for (int i = 0; i < 4; ++i)
#pragma unroll
    for (int j = 0; j < 2; ++j) acc[i][j] = (f32x4){0.f, 0.f, 0.f, 0.f};
  gemm_core(A, Bm, D_MODEL, mBase, nBase, acc, As, Bs);

  const int ln = threadIdx.x & 63, wv = threadIdx.x >> 6;
  const int wr = wv >> 1, wc = wv & 1;
  const int fr = ln & 15, fc = ln >> 4;

  if (y < 4) {
    const float* bias = (y < 2) ? bq : bk;
    short* Cs = (y < 2) ? qf : kf;
    const float fscale = (y < 2) ? QK_SCALE : 1.0f;
#pragma unroll
    for (int mi = 0; mi < 4; ++mi)
#pragma unroll
      for (int ni = 0; ni < 2; ++ni)
#pragma unroll
        for (int r = 0; r < 4; ++r) {
          const int m = mBase + wr * 64 + mi * 16 + fc * 4 + r;
          const int n = nBase + wc * 32 + ni * 16 + fr;
          const int b = m >> 11, l = m & (L_SEQ - 1);
          const float inv_freq = __expf(-(float)(n & ~1) * POS_COEF);
          const float ang = acc[mi][ni][r] + bias[n] + (float)l * inv_freq;
          float sv, cv;
          fast_sincos(ang, &sv, &cv);
          const int h = n >> 3, p = n & 7;
          const size_t base = ((size_t)((b << 4) + h) * L_SEQ + l) * 16;
          Cs[base + p] = (short)f2bf(cv * fscale);
          Cs[base + 8 + p] = (short)f2bf(sv * fscale);
        }
  } else {
    // Vt: PI-permuted j-rows (position [g1 g0 e2 e1 e0] holds row
    // [e2 g1 g0 e1 e0]) AND subtile-contiguous layout: each 16d x 32j
    // subtile is 1 KB contiguous, ordered [g][dlo][e] to match lane order,
    // so attention's V load is a fully-coalesced 1 KB wave read.
#pragma unroll
    for (int mi = 0; mi < 4; ++mi)
#pragma unroll
      for (int ni = 0; ni < 2; ++ni) {
        const int n = nBase + wc * 32 + ni * 16 + fr;
        const int m = mBase + wr * 64 + mi * 16 + fc * 4;
        const int b = m >> 11, l = m & (L_SEQ - 1);
        const int t = (l >> 2) & 7;
        const int tp = ((t << 1) & 6) | (t >> 2);
        const int lpos = (l & ~31) | (tp << 2);
        const int h = n >> 6, d = n & 63;
        const int jc = lpos >> 5, jlo = lpos & 31;
        const int gg = jlo >> 3, ee = jlo & 7;
        s16x4 pk;
#pragma unroll
        for (int r = 0; r < 4; ++r) pk[r] = (short)f2bf(acc[mi][ni][r]);
        const size_t off = (size_t)((b << 4) + h) * 64 * L_SEQ +
                           (size_t)(jc * 4 + (d >> 4)) * 512 + gg * 128 +
                           (d & 15) * 8 + ee;
        *(s16x4*)&Vt[off] = pk;
      }
  }
}

// ---------------------------------------------------------------- O GEMM (+residual)
__global__ __launch_bounds__(256) void ogemm_kernel(
    const short* __restrict__ A, const short* __restrict__ Bm,
    const float* __restrict__ resid, float* __restrict__ Cf) {
  __shared__ short As[128 * 64];
  __shared__ short Bs[64 * 64];
  const int mBase = blockIdx.x * 128, nBase = blockIdx.y * 64;

  f32x4 acc[4][2];
#pragma unroll
  for (int i = 0; i < 4; ++i)
#pragma unroll
    for (int j = 0; j < 2; ++j) acc[i][j] = (f32x4){0.f, 0.f, 0.f, 0.f};
  gemm_core(A, Bm, D_MODEL, mBase, nBase, acc, As, Bs);

  const int ln = threadIdx.x & 63, wv = threadIdx.x >> 6;
  const int wr = wv >> 1, wc = wv & 1;
  const int fr = ln & 15, fc = ln >> 4;
#pragma unroll
  for (int mi = 0; mi < 4; ++mi)
#pragma unroll
    for (int ni = 0; ni < 2; ++ni)
#pragma unroll
      for (int r = 0; r < 4; ++r) {
        const int m = mBase + wr * 64 + mi * 16 + fc * 4 + r;
        const int n = nBase + wc * 32 + ni * 16 + fr;
        const size_t idx = (size_t)m * D_MODEL + n;
        Cf[idx] = acc[mi][ni][r] + resid[idx];
      }
}

// ---------------------------------------------------------------- MFMA attention
// Intra-block flash-split over j: grid (B*H, 128), block = one 16-row q-group
// (qg = 127 - y, longest-first), 4 waves; wave w does tiles t = w, w+4, ...
// with private partial o/lsum (bounded scores -> pure-sum combine), LDS
// combine at the end. V loads are 1 KB fully-coalesced wave reads from the
// subtile-contiguous Vt. T14 prefetch: V/K loads for iteration t+4 are
// issued at the top of iteration t, hiding L2 latency under exp+pack+PV.
__global__ __launch_bounds__(256) void attn_mfma_kernel(
    const short* __restrict__ qf, const short* __restrict__ kf,
    const short* __restrict__ Vt, short* __restrict__ ao) {
  const int bh = blockIdx.x;
  const int qg = 127 - (int)blockIdx.y;  // longest blocks dispatch first
  const int tid = threadIdx.x;
  const int w = tid >> 6;
  const int lane = tid & 63;
  const int g = lane >> 4;
  const int q16 = lane & 15;
  const int qglob = qg * 16 + q16;
  const int ntiles = (qg >> 2) + 1;

  __shared__ float ol[4][16][68];  // stride 68: 2-way bank aliasing only
  __shared__ float ll[4][16];

  const short* qf_h = qf + (size_t)bh * L_SEQ * 16;
  const short* kf_h = kf + (size_t)bh * L_SEQ * 16;
  const short* Vt_h = Vt + (size_t)bh * 64 * L_SEQ;
  const int b = bh >> 4, h = bh & 15;

  bf16x8 qfrag = {0, 0, 0, 0, 0, 0, 0, 0};
  if (g < 2) qfrag = *(const bf16x8*)(qf_h + (size_t)qglob * 16 + g * 8);

  f32x4 o[4];
#pragma unroll
  for (int dc = 0; dc < 4; ++dc) o[dc] = (f32x4){0.f, 0.f, 0.f, 0.f};
  float lsum = 0.f;

  bf16x8 vA[4], vB[4], kc[4];
#pragma unroll
  for (int jt = 0; jt < 4; ++jt) kc[jt] = (bf16x8){0, 0, 0, 0, 0, 0, 0, 0};
  if (w < ntiles) {
#pragma unroll
    for (int dc = 0; dc < 4; ++dc) {
      vA[dc] = *(const bf16x8*)(Vt_h + ((size_t)((2 * w) * 4 + dc) << 9) +
                                lane * 8);
      vB[dc] = *(const bf16x8*)(Vt_h + ((size_t)((2 * w + 1) * 4 + dc) << 9) +
                                lane * 8);
    }
    if (g < 2) {
#pragma unroll
      for (int jt = 0; jt < 4; ++jt)
        kc[jt] = *(const bf16x8*)(kf_h +
                                  (size_t)((w << 6) + jt * 16 + q16) * 16 +
                                  g * 8);
    }
  }

#pragma unroll 1
  for (int t = w; t < ntiles; t += 4) {
    const int j0 = t << 6;
    const int tn = t + 4;

    // prefetch V/K for this wave's NEXT tile (consumed next iteration)
    bf16x8 vAn[4], vBn[4], kn[4];
#pragma unroll
    for (int jt = 0; jt < 4; ++jt) kn[jt] = kc[jt];
#pragma unroll
    for (int dc = 0; dc < 4; ++dc) {
      vAn[dc] = vA[dc];
      vBn[dc] = vB[dc];
    }
    if (tn < ntiles) {
#pragma unroll
      for (int dc = 0; dc < 4; ++dc) {
        vAn[dc] = *(const bf16x8*)(Vt_h + ((size_t)((2 * tn) * 4 + dc) << 9) +
                                   lane * 8);
        vBn[dc] = *(const bf16x8*)(Vt_h +
                                   ((size_t)((2 * tn + 1) * 4 + dc) << 9) +
                                   lane * 8);
      }
      if (g < 2) {
#pragma unroll
        for (int jt = 0; jt < 4; ++jt)
          kn[jt] = *(const bf16x8*)(kf_h +
                                    (size_t)((tn << 6) + jt * 16 + q16) * 16 +
                                    g * 8);
      }
    }

    // QK^T (swapped): lane holds q=q16, j = j0 + jt*16 + g*4 + r
    f32x4 s[4];
#pragma unroll
    for (int jt = 0; jt < 4; ++jt)
      s[jt] = __builtin_amdgcn_mfma_f32_16x16x32_bf16(
          kc[jt], qfrag, (f32x4){0.f, 0.f, 0.f, 0.f}, 0, 0, 0);

    // causal mask (diagonal tile only)
    if (t == ntiles - 1) {
#pragma unroll
      for (int jt = 0; jt < 4; ++jt)
#pragma unroll
        for (int r = 0; r < 4; ++r)
          if (j0 + jt * 16 + g * 4 + r > qglob) s[jt][r] = -INFINITY;
    }

    // exp + per-lane partial sum (P stays in registers)
    float ex[4][4];
#pragma unroll
    for (int jt = 0; jt < 4; ++jt)
#pragma unroll
      for (int r = 0; r < 4; ++r) {
        ex[jt][r] = __expf(s[jt][r]);
        lsum += ex[jt][r];
      }

    // PV: B-frag slot e -> (jt = 2c + (e>>2), r = e&3), all lane-local.
    // Pack via v_cvt_pk_bf16_f32 (RNE, 2 f32 -> 1 dword of 2 bf16).
#pragma unroll
    for (int c = 0; c < 2; ++c) {
      union {
        unsigned u[4];
        bf16x8 v;
      } pb;
#pragma unroll
      for (int hw = 0; hw < 2; ++hw) {
        asm("v_cvt_pk_bf16_f32 %0, %1, %2"
            : "=v"(pb.u[hw * 2 + 0])
            : "v"(ex[2 * c + hw][0]), "v"(ex[2 * c + hw][1]));
        asm("v_cvt_pk_bf16_f32 %0, %1, %2"
            : "=v"(pb.u[hw * 2 + 1])
            : "v"(ex[2 * c + hw][2]), "v"(ex[2 * c + hw][3]));
      }
      const bf16x8* vfc = c ? vB : vA;
#pragma unroll
      for (int dc = 0; dc < 4; ++dc)
        o[dc] = __builtin_amdgcn_mfma_f32_16x16x32_bf16(vfc[dc], pb.v, o[dc],
                                                        0, 0, 0);
    }

    // rotate prefetched regs
#pragma unroll
    for (int jt = 0; jt < 4; ++jt) kc[jt] = kn[jt];
#pragma unroll
    for (int dc = 0; dc < 4; ++dc) {
      vA[dc] = vAn[dc];
      vB[dc] = vBn[dc];
    }
  }

  // ---- combine the 4 waves' partials via LDS
  lsum += __shfl_xor(lsum, 16);
  lsum += __shfl_xor(lsum, 32);
  if (g == 0) ll[w][q16] = lsum;
#pragma unroll
  for (int dc = 0; dc < 4; ++dc)
    *(f32x4*)&ol[w][q16][dc * 16 + g * 4] = o[dc];
  __syncthreads();

  // wave w normalizes d-range [w*16, w*16+16)
  const float lt = (ll[0][q16] + ll[1][q16]) + (ll[2][q16] + ll[3][q16]);
  const float inv = 1.f / lt;
  const int d0 = w * 16 + g * 4;
  s16x4 pk;
#pragma unroll
  for (int r = 0; r < 4; ++r) {
    const float v = ((ol[0][q16][d0 + r] + ol[1][q16][d0 + r]) +
                     (ol[2][q16][d0 + r] + ol[3][q16][d0 + r]));
    pk[r] = (short)f2bf(v * inv);
  }
  short* orow = ao + ((size_t)(b * L_SEQ + qglob)) * D_MODEL + h * 64;
  *(s16x4*)&orow[d0] = pk;
}

// ---------------------------------------------------------------- layernorm (in place)
__global__ __launch_bounds__(256) void ln_kernel(float* __restrict__ io,
                                                 const float* __restrict__ gamma,
                                                 const float* __restrict__ beta) {
  const int row = blockIdx.x;
  float* p = io + (size_t)row * D_MODEL;
  const int tid = threadIdx.x;
  float4 x = ((const float4*)p)[tid];
  float s = x.x + x.y + x.z + x.w;
  float sq = x.x * x.x + x.y * x.y + x.z * x.z + x.w * x.w;
  s = wave_reduce_sum(s);
  sq = wave_reduce_sum(sq);
  __shared__ float ss[4], ssq[4];
  const int w = tid >> 6, lane = tid & 63;
  if (lane == 0) {
    ss[w] = s;
    ssq[w] = sq;
  }
  __syncthreads();
  s = ss[0] + ss[1] + ss[2] + ss[3];
  sq = ssq[0] + ssq[1] + ssq[2] + ssq[3];
  const float mean = s * (1.f / D_MODEL);
  const float var = sq * (1.f / D_MODEL) - mean * mean;
  const float rstd = rsqrtf(var + LN_EPS);
  const float4 g = ((const float4*)gamma)[tid];
  const float4 bt = ((const float4*)beta)[tid];
  float4 y;
  y.x = (x.x - mean) * rstd * g.x + bt.x;
  y.y = (x.y - mean) * rstd * g.y + bt.y;
  y.z = (x.z - mean) * rstd * g.z + bt.z;
  y.w = (x.w - mean) * rstd * g.w + bt.w;
  ((float4*)p)[tid] = y;
}

// ---------------------------------------------------------------- launch
extern "C" void kernel_launch(void* const* d_in, const int* in_sizes, int n_in,
                              void* d_out, int out_size, void* d_ws,
                              size_t ws_size, hipStream_t stream) {
  const float* x_real = (const float*)d_in[0];
  const float* x_imag = (const float*)d_in[1];
  const float* Wq = (const float*)d_in[2];
  const float* bq = (const float*)d_in[3];
  const float* Wk = (const float*)d_in[4];
  const float* bk = (const float*)d_in[5];
  const float* Wv = (const float*)d_in[6];
  const float* Wo = (const float*)d_in[7];
  const float* gamma = (const float*)d_in[8];
  const float* beta = (const float*)d_in[9];

  const size_t n_x = (size_t)B_SZ * L_SEQ * D_MODEL;        // 4M
  const size_t n_w = (size_t)D_MODEL * D_MODEL;             // 1M
  const size_t n_wp = (size_t)N_PHASE * D_MODEL;            // 128K
  const size_t n_qf = (size_t)B_SZ * N_HEADS * L_SEQ * 16;  // 1M

  short* xi_bf = (short*)d_ws;
  short* xr_bf = xi_bf + n_x;  // later reused as ao_bf
  short* Wq_bf = xr_bf + n_x;
  short* Wk_bf = Wq_bf + n_wp;
  short* Wv_bf = Wk_bf + n_wp;
  short* Wo_bf = Wv_bf + n_w;
  short* qf = Wo_bf + n_w;
  short* kf = qf + n_qf;
  short* Vt = kf + n_qf;  // 4M shorts
  short* ao_bf = xr_bf;   // alias: x_real bf16 dead after V GEMM

  float* outr = (float*)d_out;
  float* outi = outr + n_x;

  const dim3 blk(256);
  const int M = B_SZ * L_SEQ;  // 4096

  const int cvt_blocks = (NX4 + NWP4 + NW4 + 255) / 256;
  cvtall_kernel<<<dim3(cvt_blocks), blk, 0, stream>>>(
      x_real, x_imag, Wq, Wk, Wv, Wo, xr_bf, xi_bf, Wq_bf, Wk_bf, Wv_bf,
      Wo_bf, outi);

  qkv_kernel<<<dim3(M / 128, 20), blk, 0, stream>>>(
      xi_bf, xr_bf, Wq_bf, Wk_bf, Wv_bf, bq, bk, qf, kf, Vt);
  attn_mfma_kernel<<<dim3(B_SZ * N_HEADS, 128), blk, 0, stream>>>(qf, kf, Vt,
                                                                  ao_bf);
  ogemm_kernel<<<dim3(M / 128, D_MODEL / 64), blk, 0, stream>>>(
      ao_bf, Wo_bf, x_real, outr);
  ln_kernel<<<dim3(M), blk, 0, stream>>>(outr, gamma, beta);
}

// Round 16
// 91.718 us; speedup vs baseline: 1.1855x; 1.0448x over previous
//
#include <hip/hip_runtime.h>
#include <math.h>

#define D_MODEL 1024
#define N_HEADS 16
#define N_PHASE 128
#define HEAD_DIM 64
#define B_SZ 2
#define L_SEQ 2048
#define QK_SCALE 0.35355339059327373f   // 1/sqrt(8)
#define LN_EPS 1e-5f
#define POS_COEF 0.07195578415606394f   // ln(10000)/128
#define INV_2PI 0.15915494309189535f

typedef __attribute__((ext_vector_type(8))) short bf16x8;
typedef __attribute__((ext_vector_type(4))) short s16x4;
typedef __attribute__((ext_vector_type(4))) float f32x4;

// ---------------------------------------------------------------- helpers
__device__ __forceinline__ float wave_reduce_sum(float v) {
#pragma unroll
  for (int off = 32; off > 0; off >>= 1) v += __shfl_xor(v, off);
  return v;
}
// f32 -> bf16 (RNE)
__device__ __forceinline__ unsigned short f2bf(float x) {
  unsigned u = __float_as_uint(x);
  u += 0x7fffu + ((u >> 16) & 1u);
  return (unsigned short)(u >> 16);
}
__device__ __forceinline__ void gload16(const short* g, short* l) {
  __builtin_amdgcn_global_load_lds(
      (const __attribute__((address_space(1))) void*)g,
      (__attribute__((address_space(3))) void*)l, 16, 0, 0);
}
// hw sin/cos with explicit range reduction (v_sin/v_cos take REVOLUTIONS,
// limited domain -> reduce to [-0.5, 0.5] rev with rndne first)
__device__ __forceinline__ void fast_sincos(float ang, float* s, float* c) {
  float rev = ang * INV_2PI;
  rev = rev - rintf(rev);
  *c = __builtin_amdgcn_cosf(rev);
  *s = __builtin_amdgcn_sinf(rev);
}

// ---------------------------------------------------------------- merged converts
#define NX4 ((B_SZ * L_SEQ * D_MODEL) / 4)
#define NWP4 ((N_PHASE * D_MODEL) / 4)
#define NW4 ((D_MODEL * D_MODEL) / 4)
__device__ __forceinline__ s16x4 cvt4(float4 v) {
  s16x4 o;
  o[0] = (short)f2bf(v.x);
  o[1] = (short)f2bf(v.y);
  o[2] = (short)f2bf(v.z);
  o[3] = (short)f2bf(v.w);
  return o;
}
__global__ __launch_bounds__(256) void cvtall_kernel(
    const float* __restrict__ x_real, const float* __restrict__ x_imag,
    const float* __restrict__ Wq, const float* __restrict__ Wk,
    const float* __restrict__ Wv, const float* __restrict__ Wo,
    short* __restrict__ xr_bf, short* __restrict__ xi_bf,
    short* __restrict__ Wq_bf, short* __restrict__ Wk_bf,
    short* __restrict__ Wv_bf, short* __restrict__ Wo_bf,
    float* __restrict__ outi) {
  const int i = blockIdx.x * 256 + threadIdx.x;
  if (i < NX4) {
    const float4 vi = ((const float4*)x_imag)[i];
    ((float4*)outi)[i] = vi;
    ((s16x4*)xi_bf)[i] = cvt4(vi);
    ((s16x4*)xr_bf)[i] = cvt4(((const float4*)x_real)[i]);
  } else if (i < NX4 + NWP4) {
    const int j = i - NX4;
    ((s16x4*)Wq_bf)[j] = cvt4(((const float4*)Wq)[j]);
    ((s16x4*)Wk_bf)[j] = cvt4(((const float4*)Wk)[j]);
  } else if (i < NX4 + NWP4 + NW4) {
    const int j = i - NX4 - NWP4;
    ((s16x4*)Wv_bf)[j] = cvt4(((const float4*)Wv)[j]);
    ((s16x4*)Wo_bf)[j] = cvt4(((const float4*)Wo)[j]);
  }
}

// ---------------------------------------------------------------- GEMM core
// 128x64 tile, BK=64 (2 barriers per 64-wide K step -> half the drains of
// BK=32). Staging: 8 rows x 8 chunks of 8 shorts per gload16; involution
// swizzle chunk ^= (row&7) on the GLOBAL source (gload_lds dest is linear);
// read side uses p = (kk*4+fc) ^ (fr&7) -> 2-way bank spread (free).
__device__ __forceinline__ void gemm_core(const short* __restrict__ A,
                                          const short* __restrict__ Bm, int K,
                                          int mBase, int nBase,
                                          f32x4 acc[4][2], short* As,
                                          short* Bs) {
  const int tid = threadIdx.x;
  const int wv = tid >> 6, ln = tid & 63;
  const int wr = wv >> 1, wc = wv & 1;
  const int fr = ln & 15, fc = ln >> 4;
  const int row8 = ln >> 3;              // 0..7 within an 8-row stripe
  const int cg = (ln & 7) ^ row8;        // swizzled global source chunk
  const short* ga = A + (size_t)(mBase + wv * 32 + row8) * K + cg * 8;
  const short* gb = Bm + (size_t)(nBase + wv * 16 + row8) * K + cg * 8;
  short* la = As + wv * 2048;            // 32 rows x 64 cols per wave
  short* lb = Bs + wv * 1024;            // 16 rows x 64 cols per wave
  const int swz = fr & 7;

  for (int k0 = 0; k0 < K; k0 += 64) {
    __syncthreads();
#pragma unroll
    for (int i = 0; i < 4; ++i)
      gload16(ga + k0 + (size_t)(8 * i) * K, la + i * 512);
#pragma unroll
    for (int i = 0; i < 2; ++i)
      gload16(gb + k0 + (size_t)(8 * i) * K, lb + i * 512);
    __syncthreads();

    bf16x8 af[2][4], bfr[2][2];
#pragma unroll
    for (int kk = 0; kk < 2; ++kk) {
      const int pc = ((kk * 4 + fc) ^ swz) * 8;
#pragma unroll
      for (int mi = 0; mi < 4; ++mi)
        af[kk][mi] =
            *(const bf16x8*)&As[(wr * 64 + mi * 16 + fr) * 64 + pc];
#pragma unroll
      for (int ni = 0; ni < 2; ++ni)
        bfr[kk][ni] =
            *(const bf16x8*)&Bs[(wc * 32 + ni * 16 + fr) * 64 + pc];
    }
#pragma unroll
    for (int kk = 0; kk < 2; ++kk)
#pragma unroll
      for (int mi = 0; mi < 4; ++mi)
#pragma unroll
        for (int ni = 0; ni < 2; ++ni)
          acc[mi][ni] = __builtin_amdgcn_mfma_f32_16x16x32_bf16(
              af[kk][mi], bfr[kk][ni], acc[mi][ni], 0, 0, 0);
  }
}

// ---------------------------------------------------------------- fused QKV projections
// grid (M/128, 20): y in [0,2) -> Q phase, [2,4) -> K phase, [4,20) -> V GEMM
__global__ __launch_bounds__(256) void qkv_kernel(
    const short* __restrict__ xi, const short* __restrict__ xr,
    const short* __restrict__ WqB, const short* __restrict__ WkB,
    const short* __restrict__ WvB, const float* __restrict__ bq,
    const float* __restrict__ bk, short* __restrict__ qf,
    short* __restrict__ kf, short* __restrict__ Vt) {
  __shared__ short As[128 * 64];
  __shared__ short Bs[64 * 64];
  const int y = blockIdx.y;
  const int mBase = blockIdx.x * 128;
  const short* A;
  const short* Bm;
  int nBase;
  if (y < 4) {
    A = xi;
    Bm = (y < 2) ? WqB : WkB;
    nBase = (y & 1) * 64;
  } else {
    A = xr;
    Bm = WvB;
    nBase = (y - 4) * 64;
  }

  f32x4 acc[4][2];
#pragma unroll
  for (int i = 0; i < 4; ++i)
#pragma unroll
    for (int j = 0; j < 2; ++j) acc[i][j] = (f32x4){0.f, 0.f, 0.f, 0.f};
  gemm_core(A, Bm, D_MODEL, mBase, nBase, acc, As, Bs);

  const int ln = threadIdx.x & 63, wv = threadIdx.x >> 6;
  const int wr = wv >> 1, wc = wv & 1;
  const int fr = ln & 15, fc = ln >> 4;

  if (y < 4) {
    const float* bias = (y < 2) ? bq : bk;
    short* Cs = (y < 2) ? qf : kf;
    const float fscale = (y < 2) ? QK_SCALE : 1.0f;
#pragma unroll
    for (int mi = 0; mi < 4; ++mi)
#pragma unroll
      for (int ni = 0; ni < 2; ++ni)
#pragma unroll
        for (int r = 0; r < 4; ++r) {
          const int m = mBase + wr * 64 + mi * 16 + fc * 4 + r;
          const int n = nBase + wc * 32 + ni * 16 + fr;
          const int b = m >> 11, l = m & (L_SEQ - 1);
          const float inv_freq = __expf(-(float)(n & ~1) * POS_COEF);
          const float ang = acc[mi][ni][r] + bias[n] + (float)l * inv_freq;
          float sv, cv;
          fast_sincos(ang, &sv, &cv);
          const int h = n >> 3, p = n & 7;
          const size_t base = ((size_t)((b << 4) + h) * L_SEQ + l) * 16;
          Cs[base + p] = (short)f2bf(cv * fscale);
          Cs[base + 8 + p] = (short)f2bf(sv * fscale);
        }
  } else {
    // Vt: PI-permuted j-rows (position [g1 g0 e2 e1 e0] holds row
    // [e2 g1 g0 e1 e0]) AND subtile-contiguous layout: each 16d x 32j
    // subtile is 1 KB contiguous, ordered [g][dlo][e] to match lane order,
    // so attention's V load is a fully-coalesced 1 KB wave read.
#pragma unroll
    for (int mi = 0; mi < 4; ++mi)
#pragma unroll
      for (int ni = 0; ni < 2; ++ni) {
        const int n = nBase + wc * 32 + ni * 16 + fr;
        const int m = mBase + wr * 64 + mi * 16 + fc * 4;
        const int b = m >> 11, l = m & (L_SEQ - 1);
        const int t = (l >> 2) & 7;
        const int tp = ((t << 1) & 6) | (t >> 2);
        const int lpos = (l & ~31) | (tp << 2);
        const int h = n >> 6, d = n & 63;
        const int jc = lpos >> 5, jlo = lpos & 31;
        const int gg = jlo >> 3, ee = jlo & 7;
        s16x4 pk;
#pragma unroll
        for (int r = 0; r < 4; ++r) pk[r] = (short)f2bf(acc[mi][ni][r]);
        const size_t off = (size_t)((b << 4) + h) * 64 * L_SEQ +
                           (size_t)(jc * 4 + (d >> 4)) * 512 + gg * 128 +
                           (d & 15) * 8 + ee;
        *(s16x4*)&Vt[off] = pk;
      }
  }
}

// ---------------------------------------------------------------- O GEMM (+residual)
__global__ __launch_bounds__(256) void ogemm_kernel(
    const short* __restrict__ A, const short* __restrict__ Bm,
    const float* __restrict__ resid, float* __restrict__ Cf) {
  __shared__ short As[128 * 64];
  __shared__ short Bs[64 * 64];
  const int mBase = blockIdx.x * 128, nBase = blockIdx.y * 64;

  f32x4 acc[4][2];
#pragma unroll
  for (int i = 0; i < 4; ++i)
#pragma unroll
    for (int j = 0; j < 2; ++j) acc[i][j] = (f32x4){0.f, 0.f, 0.f, 0.f};
  gemm_core(A, Bm, D_MODEL, mBase, nBase, acc, As, Bs);

  const int ln = threadIdx.x & 63, wv = threadIdx.x >> 6;
  const int wr = wv >> 1, wc = wv & 1;
  const int fr = ln & 15, fc = ln >> 4;
#pragma unroll
  for (int mi = 0; mi < 4; ++mi)
#pragma unroll
    for (int ni = 0; ni < 2; ++ni)
#pragma unroll
      for (int r = 0; r < 4; ++r) {
        const int m = mBase + wr * 64 + mi * 16 + fc * 4 + r;
        const int n = nBase + wc * 32 + ni * 16 + fr;
        const size_t idx = (size_t)m * D_MODEL + n;
        Cf[idx] = acc[mi][ni][r] + resid[idx];
      }
}

// ---------------------------------------------------------------- MFMA attention
// Intra-block flash-split over j: grid (B*H, 128), block = one 16-row q-group
// (qg = 127 - y, longest-first), 4 waves; wave w does tiles t = w, w+4, ...
// with private partial o/lsum (bounded scores -> pure-sum combine), LDS
// combine at the end. V loads are 1 KB fully-coalesced wave reads from the
// subtile-contiguous Vt. P-pack uses v_cvt_pk_bf16_f32. (r15's T14 prefetch
// reverted: +24 VGPR cost occupancy 34->25% on an already-VALU-bound kernel.)
__global__ __launch_bounds__(256) void attn_mfma_kernel(
    const short* __restrict__ qf, const short* __restrict__ kf,
    const short* __restrict__ Vt, short* __restrict__ ao) {
  const int bh = blockIdx.x;
  const int qg = 127 - (int)blockIdx.y;  // longest blocks dispatch first
  const int tid = threadIdx.x;
  const int w = tid >> 6;
  const int lane = tid & 63;
  const int g = lane >> 4;
  const int q16 = lane & 15;
  const int qglob = qg * 16 + q16;
  const int ntiles = (qg >> 2) + 1;

  __shared__ float ol[4][16][68];  // stride 68: 2-way bank aliasing only
  __shared__ float ll[4][16];

  const short* qf_h = qf + (size_t)bh * L_SEQ * 16;
  const short* kf_h = kf + (size_t)bh * L_SEQ * 16;
  const short* Vt_h = Vt + (size_t)bh * 64 * L_SEQ;
  const int b = bh >> 4, h = bh & 15;

  bf16x8 qfrag = {0, 0, 0, 0, 0, 0, 0, 0};
  if (g < 2) qfrag = *(const bf16x8*)(qf_h + (size_t)qglob * 16 + g * 8);

  f32x4 o[4];
#pragma unroll
  for (int dc = 0; dc < 4; ++dc) o[dc] = (f32x4){0.f, 0.f, 0.f, 0.f};
  float lsum = 0.f;

#pragma unroll 1
  for (int t = w; t < ntiles; t += 4) {
    const int j0 = t << 6;

    // V for this tile: subtile (2t+c)*4+dc, fully-coalesced 1 KB reads
    bf16x8 vf0[4], vf1[4];
#pragma unroll
    for (int dc = 0; dc < 4; ++dc)
      vf0[dc] = *(const bf16x8*)(Vt_h + ((size_t)((2 * t) * 4 + dc) << 9) +
                                 lane * 8);

    // K fragments for this tile
    bf16x8 kfr[4];
#pragma unroll
    for (int jt = 0; jt < 4; ++jt) {
      kfr[jt] = (bf16x8){0, 0, 0, 0, 0, 0, 0, 0};
      if (g < 2)
        kfr[jt] =
            *(const bf16x8*)(kf_h + (size_t)(j0 + jt * 16 + q16) * 16 + g * 8);
    }

    // QK^T (swapped): lane holds q=q16, j = j0 + jt*16 + g*4 + r
    f32x4 s[4];
#pragma unroll
    for (int jt = 0; jt < 4; ++jt)
      s[jt] = __builtin_amdgcn_mfma_f32_16x16x32_bf16(
          kfr[jt], qfrag, (f32x4){0.f, 0.f, 0.f, 0.f}, 0, 0, 0);

#pragma unroll
    for (int dc = 0; dc < 4; ++dc)
      vf1[dc] = *(const bf16x8*)(Vt_h + ((size_t)((2 * t + 1) * 4 + dc) << 9) +
                                 lane * 8);

    // causal mask (diagonal tile only)
    if (t == ntiles - 1) {
#pragma unroll
      for (int jt = 0; jt < 4; ++jt)
#pragma unroll
        for (int r = 0; r < 4; ++r)
          if (j0 + jt * 16 + g * 4 + r > qglob) s[jt][r] = -INFINITY;
    }

    // exp + per-lane partial sum (P stays in registers)
    float ex[4][4];
#pragma unroll
    for (int jt = 0; jt < 4; ++jt)
#pragma unroll
      for (int r = 0; r < 4; ++r) {
        ex[jt][r] = __expf(s[jt][r]);
        lsum += ex[jt][r];
      }

    // PV: B-frag slot e -> (jt = 2c + (e>>2), r = e&3), all lane-local.
    // Pack via v_cvt_pk_bf16_f32 (RNE, 2 f32 -> 1 dword of 2 bf16).
#pragma unroll
    for (int c = 0; c < 2; ++c) {
      union {
        unsigned u[4];
        bf16x8 v;
      } pb;
#pragma unroll
      for (int hw = 0; hw < 2; ++hw) {
        asm("v_cvt_pk_bf16_f32 %0, %1, %2"
            : "=v"(pb.u[hw * 2 + 0])
            : "v"(ex[2 * c + hw][0]), "v"(ex[2 * c + hw][1]));
        asm("v_cvt_pk_bf16_f32 %0, %1, %2"
            : "=v"(pb.u[hw * 2 + 1])
            : "v"(ex[2 * c + hw][2]), "v"(ex[2 * c + hw][3]));
      }
      const bf16x8* vfc = c ? vf1 : vf0;
#pragma unroll
      for (int dc = 0; dc < 4; ++dc)
        o[dc] = __builtin_amdgcn_mfma_f32_16x16x32_bf16(vfc[dc], pb.v, o[dc],
                                                        0, 0, 0);
    }
  }

  // ---- combine the 4 waves' partials via LDS
  lsum += __shfl_xor(lsum, 16);
  lsum += __shfl_xor(lsum, 32);
  if (g == 0) ll[w][q16] = lsum;
#pragma unroll
  for (int dc = 0; dc < 4; ++dc)
    *(f32x4*)&ol[w][q16][dc * 16 + g * 4] = o[dc];
  __syncthreads();

  // wave w normalizes d-range [w*16, w*16+16)
  const float lt = (ll[0][q16] + ll[1][q16]) + (ll[2][q16] + ll[3][q16]);
  const float inv = 1.f / lt;
  const int d0 = w * 16 + g * 4;
  s16x4 pk;
#pragma unroll
  for (int r = 0; r < 4; ++r) {
    const float v = ((ol[0][q16][d0 + r] + ol[1][q16][d0 + r]) +
                     (ol[2][q16][d0 + r] + ol[3][q16][d0 + r]));
    pk[r] = (short)f2bf(v * inv);
  }
  short* orow = ao + ((size_t)(b * L_SEQ + qglob)) * D_MODEL + h * 64;
  *(s16x4*)&orow[d0] = pk;
}

// ---------------------------------------------------------------- layernorm (in place)
__global__ __launch_bounds__(256) void ln_kernel(float* __restrict__ io,
                                                 const float* __restrict__ gamma,
                                                 const float* __restrict__ beta) {
  const int row = blockIdx.x;
  float* p = io + (size_t)row * D_MODEL;
  const int tid = threadIdx.x;
  float4 x = ((const float4*)p)[tid];
  float s = x.x + x.y + x.z + x.w;
  float sq = x.x * x.x + x.y * x.y + x.z * x.z + x.w * x.w;
  s = wave_reduce_sum(s);
  sq = wave_reduce_sum(sq);
  __shared__ float ss[4], ssq[4];
  const int w = tid >> 6, lane = tid & 63;
  if (lane == 0) {
    ss[w] = s;
    ssq[w] = sq;
  }
  __syncthreads();
  s = ss[0] + ss[1] + ss[2] + ss[3];
  sq = ssq[0] + ssq[1] + ssq[2] + ssq[3];
  const float mean = s * (1.f / D_MODEL);
  const float var = sq * (1.f / D_MODEL) - mean * mean;
  const float rstd = rsqrtf(var + LN_EPS);
  const float4 g = ((const float4*)gamma)[tid];
  const float4 bt = ((const float4*)beta)[tid];
  float4 y;
  y.x = (x.x - mean) * rstd * g.x + bt.x;
  y.y = (x.y - mean) * rstd * g.y + bt.y;
  y.z = (x.z - mean) * rstd * g.z + bt.z;
  y.w = (x.w - mean) * rstd * g.w + bt.w;
  ((float4*)p)[tid] = y;
}

// ---------------------------------------------------------------- launch
extern "C" void kernel_launch(void* const* d_in, const int* in_sizes, int n_in,
                              void* d_out, int out_size, void* d_ws,
                              size_t ws_size, hipStream_t stream) {
  const float* x_real = (const float*)d_in[0];
  const float* x_imag = (const float*)d_in[1];
  const float* Wq = (const float*)d_in[2];
  const float* bq = (const float*)d_in[3];
  const float* Wk = (const float*)d_in[4];
  const float* bk = (const float*)d_in[5];
  const float* Wv = (const float*)d_in[6];
  const float* Wo = (const float*)d_in[7];
  const float* gamma = (const float*)d_in[8];
  const float* beta = (const float*)d_in[9];

  const size_t n_x = (size_t)B_SZ * L_SEQ * D_MODEL;        // 4M
  const size_t n_w = (size_t)D_MODEL * D_MODEL;             // 1M
  const size_t n_wp = (size_t)N_PHASE * D_MODEL;            // 128K
  const size_t n_qf = (size_t)B_SZ * N_HEADS * L_SEQ * 16;  // 1M

  short* xi_bf = (short*)d_ws;
  short* xr_bf = xi_bf + n_x;  // later reused as ao_bf
  short* Wq_bf = xr_bf + n_x;
  short* Wk_bf = Wq_bf + n_wp;
  short* Wv_bf = Wk_bf + n_wp;
  short* Wo_bf = Wv_bf + n_w;
  short* qf = Wo_bf + n_w;
  short* kf = qf + n_qf;
  short* Vt = kf + n_qf;  // 4M shorts
  short* ao_bf = xr_bf;   // alias: x_real bf16 dead after V GEMM

  float* outr = (float*)d_out;
  float* outi = outr + n_x;

  const dim3 blk(256);
  const int M = B_SZ * L_SEQ;  // 4096

  const int cvt_blocks = (NX4 + NWP4 + NW4 + 255) / 256;
  cvtall_kernel<<<dim3(cvt_blocks), blk, 0, stream>>>(
      x_real, x_imag, Wq, Wk, Wv, Wo, xr_bf, xi_bf, Wq_bf, Wk_bf, Wv_bf,
      Wo_bf, outi);

  qkv_kernel<<<dim3(M / 128, 20), blk, 0, stream>>>(
      xi_bf, xr_bf, Wq_bf, Wk_bf, Wv_bf, bq, bk, qf, kf, Vt);
  attn_mfma_kernel<<<dim3(B_SZ * N_HEADS, 128), blk, 0, stream>>>(qf, kf, Vt,
                                                                  ao_bf);
  ogemm_kernel<<<dim3(M / 128, D_MODEL / 64), blk, 0, stream>>>(
      ao_bf, Wo_bf, x_real, outr);
  ln_kernel<<<dim3(M), blk, 0, stream>>>(outr, gamma, beta);
}

// Round 17
// 89.978 us; speedup vs baseline: 1.2084x; 1.0193x over previous
//
#include <hip/hip_runtime.h>
#include <math.h>

#define D_MODEL 1024
#define N_HEADS 16
#define N_PHASE 128
#define HEAD_DIM 64
#define B_SZ 2
#define L_SEQ 2048
#define QK_SCALE 0.35355339059327373f   // 1/sqrt(8)
#define LN_EPS 1e-5f
#define POS_COEF 0.07195578415606394f   // ln(10000)/128
#define INV_2PI 0.15915494309189535f

typedef __attribute__((ext_vector_type(8))) short bf16x8;
typedef __attribute__((ext_vector_type(4))) short s16x4;
typedef __attribute__((ext_vector_type(4))) float f32x4;

// ---------------------------------------------------------------- helpers
__device__ __forceinline__ float wave_reduce_sum(float v) {
#pragma unroll
  for (int off = 32; off > 0; off >>= 1) v += __shfl_xor(v, off);
  return v;
}
// f32 -> bf16 (RNE)
__device__ __forceinline__ unsigned short f2bf(float x) {
  unsigned u = __float_as_uint(x);
  u += 0x7fffu + ((u >> 16) & 1u);
  return (unsigned short)(u >> 16);
}
__device__ __forceinline__ void gload16(const short* g, short* l) {
  __builtin_amdgcn_global_load_lds(
      (const __attribute__((address_space(1))) void*)g,
      (__attribute__((address_space(3))) void*)l, 16, 0, 0);
}
// hw sin/cos with explicit range reduction (v_sin/v_cos take REVOLUTIONS,
// limited domain -> reduce to [-0.5, 0.5] rev with rndne first)
__device__ __forceinline__ void fast_sincos(float ang, float* s, float* c) {
  float rev = ang * INV_2PI;
  rev = rev - rintf(rev);
  *c = __builtin_amdgcn_cosf(rev);
  *s = __builtin_amdgcn_sinf(rev);
}

// ---------------------------------------------------------------- merged converts
#define NX4 ((B_SZ * L_SEQ * D_MODEL) / 4)
#define NWP4 ((N_PHASE * D_MODEL) / 4)
#define NW4 ((D_MODEL * D_MODEL) / 4)
__device__ __forceinline__ s16x4 cvt4(float4 v) {
  s16x4 o;
  o[0] = (short)f2bf(v.x);
  o[1] = (short)f2bf(v.y);
  o[2] = (short)f2bf(v.z);
  o[3] = (short)f2bf(v.w);
  return o;
}
__global__ __launch_bounds__(256) void cvtall_kernel(
    const float* __restrict__ x_real, const float* __restrict__ x_imag,
    const float* __restrict__ Wq, const float* __restrict__ Wk,
    const float* __restrict__ Wv, const float* __restrict__ Wo,
    short* __restrict__ xr_bf, short* __restrict__ xi_bf,
    short* __restrict__ Wq_bf, short* __restrict__ Wk_bf,
    short* __restrict__ Wv_bf, short* __restrict__ Wo_bf,
    float* __restrict__ outi) {
  const int i = blockIdx.x * 256 + threadIdx.x;
  if (i < NX4) {
    const float4 vi = ((const float4*)x_imag)[i];
    ((float4*)outi)[i] = vi;
    ((s16x4*)xi_bf)[i] = cvt4(vi);
    ((s16x4*)xr_bf)[i] = cvt4(((const float4*)x_real)[i]);
  } else if (i < NX4 + NWP4) {
    const int j = i - NX4;
    ((s16x4*)Wq_bf)[j] = cvt4(((const float4*)Wq)[j]);
    ((s16x4*)Wk_bf)[j] = cvt4(((const float4*)Wk)[j]);
  } else if (i < NX4 + NWP4 + NW4) {
    const int j = i - NX4 - NWP4;
    ((s16x4*)Wv_bf)[j] = cvt4(((const float4*)Wv)[j]);
    ((s16x4*)Wo_bf)[j] = cvt4(((const float4*)Wo)[j]);
  }
}

// ---------------------------------------------------------------- GEMM core
// 128x64 tile, BK=64 (2 barriers per 64-wide K step -> half the drains of
// BK=32). Staging: 8 rows x 8 chunks of 8 shorts per gload16; involution
// swizzle chunk ^= (row&7) on the GLOBAL source (gload_lds dest is linear);
// read side uses p = (kk*4+fc) ^ (fr&7) -> 2-way bank spread (free).
__device__ __forceinline__ void gemm_core(const short* __restrict__ A,
                                          const short* __restrict__ Bm, int K,
                                          int mBase, int nBase,
                                          f32x4 acc[4][2], short* As,
                                          short* Bs) {
  const int tid = threadIdx.x;
  const int wv = tid >> 6, ln = tid & 63;
  const int wr = wv >> 1, wc = wv & 1;
  const int fr = ln & 15, fc = ln >> 4;
  const int row8 = ln >> 3;              // 0..7 within an 8-row stripe
  const int cg = (ln & 7) ^ row8;        // swizzled global source chunk
  const short* ga = A + (size_t)(mBase + wv * 32 + row8) * K + cg * 8;
  const short* gb = Bm + (size_t)(nBase + wv * 16 + row8) * K + cg * 8;
  short* la = As + wv * 2048;            // 32 rows x 64 cols per wave
  short* lb = Bs + wv * 1024;            // 16 rows x 64 cols per wave
  const int swz = fr & 7;

  for (int k0 = 0; k0 < K; k0 += 64) {
    __syncthreads();
#pragma unroll
    for (int i = 0; i < 4; ++i)
      gload16(ga + k0 + (size_t)(8 * i) * K, la + i * 512);
#pragma unroll
    for (int i = 0; i < 2; ++i)
      gload16(gb + k0 + (size_t)(8 * i) * K, lb + i * 512);
    __syncthreads();

    bf16x8 af[2][4], bfr[2][2];
#pragma unroll
    for (int kk = 0; kk < 2; ++kk) {
      const int pc = ((kk * 4 + fc) ^ swz) * 8;
#pragma unroll
      for (int mi = 0; mi < 4; ++mi)
        af[kk][mi] =
            *(const bf16x8*)&As[(wr * 64 + mi * 16 + fr) * 64 + pc];
#pragma unroll
      for (int ni = 0; ni < 2; ++ni)
        bfr[kk][ni] =
            *(const bf16x8*)&Bs[(wc * 32 + ni * 16 + fr) * 64 + pc];
    }
#pragma unroll
    for (int kk = 0; kk < 2; ++kk)
#pragma unroll
      for (int mi = 0; mi < 4; ++mi)
#pragma unroll
        for (int ni = 0; ni < 2; ++ni)
          acc[mi][ni] = __builtin_amdgcn_mfma_f32_16x16x32_bf16(
              af[kk][mi], bfr[kk][ni], acc[mi][ni], 0, 0, 0);
  }
}

// ---------------------------------------------------------------- fused QKV projections
// grid (M/128, 20): y in [0,2) -> Q phase, [2,4) -> K phase, [4,20) -> V GEMM
__global__ __launch_bounds__(256) void qkv_kernel(
    const short* __restrict__ xi, const short* __restrict__ xr,
    const short* __restrict__ WqB, const short* __restrict__ WkB,
    const short* __restrict__ WvB, const float* __restrict__ bq,
    const float* __restrict__ bk, short* __restrict__ qf,
    short* __restrict__ kf, short* __restrict__ Vt) {
  __shared__ short As[128 * 64];
  __shared__ short Bs[64 * 64];
  const int y = blockIdx.y;
  const int mBase = blockIdx.x * 128;
  const short* A;
  const short* Bm;
  int nBase;
  if (y < 4) {
    A = xi;
    Bm = (y < 2) ? WqB : WkB;
    nBase = (y & 1) * 64;
  } else {
    A = xr;
    Bm = WvB;
    nBase = (y - 4) * 64;
  }

  f32x4 acc[4][2];
#pragma unroll
  for (int i = 0; i < 4; ++i)
#pragma unroll
    for (int j = 0; j < 2; ++j) acc[i][j] = (f32x4){0.f, 0.f, 0.f, 0.f};
  gemm_core(A, Bm, D_MODEL, mBase, nBase, acc, As, Bs);

  const int ln = threadIdx.x & 63, wv = threadIdx.x >> 6;
  const int wr = wv >> 1, wc = wv & 1;
  const int fr = ln & 15, fc = ln >> 4;

  if (y < 4) {
    const float* bias = (y < 2) ? bq : bk;
    short* Cs = (y < 2) ? qf : kf;
    const float fscale = (y < 2) ? QK_SCALE : 1.0f;
#pragma unroll
    for (int mi = 0; mi < 4; ++mi)
#pragma unroll
      for (int ni = 0; ni < 2; ++ni)
#pragma unroll
        for (int r = 0; r < 4; ++r) {
          const int m = mBase + wr * 64 + mi * 16 + fc * 4 + r;
          const int n = nBase + wc * 32 + ni * 16 + fr;
          const int b = m >> 11, l = m & (L_SEQ - 1);
          const float inv_freq = __expf(-(float)(n & ~1) * POS_COEF);
          const float ang = acc[mi][ni][r] + bias[n] + (float)l * inv_freq;
          float sv, cv;
          fast_sincos(ang, &sv, &cv);
          const int h = n >> 3, p = n & 7;
          const size_t base = ((size_t)((b << 4) + h) * L_SEQ + l) * 16;
          Cs[base + p] = (short)f2bf(cv * fscale);
          Cs[base + 8 + p] = (short)f2bf(sv * fscale);
        }
  } else {
    // Vt: PI-permuted j-rows (position [g1 g0 e2 e1 e0] holds row
    // [e2 g1 g0 e1 e0]) AND subtile-contiguous layout: each 16d x 32j
    // subtile is 1 KB contiguous, ordered [g][dlo][e] to match lane order,
    // so attention's V load is a fully-coalesced 1 KB wave read.
#pragma unroll
    for (int mi = 0; mi < 4; ++mi)
#pragma unroll
      for (int ni = 0; ni < 2; ++ni) {
        const int n = nBase + wc * 32 + ni * 16 + fr;
        const int m = mBase + wr * 64 + mi * 16 + fc * 4;
        const int b = m >> 11, l = m & (L_SEQ - 1);
        const int t = (l >> 2) & 7;
        const int tp = ((t << 1) & 6) | (t >> 2);
        const int lpos = (l & ~31) | (tp << 2);
        const int h = n >> 6, d = n & 63;
        const int jc = lpos >> 5, jlo = lpos & 31;
        const int gg = jlo >> 3, ee = jlo & 7;
        s16x4 pk;
#pragma unroll
        for (int r = 0; r < 4; ++r) pk[r] = (short)f2bf(acc[mi][ni][r]);
        const size_t off = (size_t)((b << 4) + h) * 64 * L_SEQ +
                           (size_t)(jc * 4 + (d >> 4)) * 512 + gg * 128 +
                           (d & 15) * 8 + ee;
        *(s16x4*)&Vt[off] = pk;
      }
  }
}

// ---------------------------------------------------------------- O GEMM (+residual)
__global__ __launch_bounds__(256) void ogemm_kernel(
    const short* __restrict__ A, const short* __restrict__ Bm,
    const float* __restrict__ resid, float* __restrict__ Cf) {
  __shared__ short As[128 * 64];
  __shared__ short Bs[64 * 64];
  const int mBase = blockIdx.x * 128, nBase = blockIdx.y * 64;

  f32x4 acc[4][2];
#pragma unroll
  for (int i = 0; i < 4; ++i)
#pragma unroll
    for (int j = 0; j < 2; ++j) acc[i][j] = (f32x4){0.f, 0.f, 0.f, 0.f};
  gemm_core(A, Bm, D_MODEL, mBase, nBase, acc, As, Bs);

  const int ln = threadIdx.x & 63, wv = threadIdx.x >> 6;
  const int wr = wv >> 1, wc = wv & 1;
  const int fr = ln & 15, fc = ln >> 4;
#pragma unroll
  for (int mi = 0; mi < 4; ++mi)
#pragma unroll
    for (int ni = 0; ni < 2; ++ni)
#pragma unroll
      for (int r = 0; r < 4; ++r) {
        const int m = mBase + wr * 64 + mi * 16 + fc * 4 + r;
        const int n = nBase + wc * 32 + ni * 16 + fr;
        const size_t idx = (size_t)m * D_MODEL + n;
        Cf[idx] = acc[mi][ni][r] + resid[idx];
      }
}

// ---------------------------------------------------------------- MFMA attention
// Paired flash-split: grid (B*H, 64); block owns q-groups qgA = y (short)
// and qgB = 127 - y (long). qgA's causal j-range is a prefix of qgB's, so
// one t-loop serves both: K/V for tile t loaded ONCE, QK/exp/pack/PV done
// for B always and for A when t < ntilesA. Iterations drop 26%, K/V loads
// ~halve, waves halve (8192, ~8 iter each) -> prologue/epilogue amortized.
// Per-q-row math identical to the split version (same order) -> same bits.
__global__ __launch_bounds__(256) void attn_mfma_kernel(
    const short* __restrict__ qf, const short* __restrict__ kf,
    const short* __restrict__ Vt, short* __restrict__ ao) {
  const int bh = blockIdx.x;
  const int qgA = (int)blockIdx.y;        // short extent
  const int qgB = 127 - (int)blockIdx.y;  // long extent
  const int tid = threadIdx.x;
  const int w = tid >> 6;
  const int lane = tid & 63;
  const int g = lane >> 4;
  const int q16 = lane & 15;
  const int qglobA = qgA * 16 + q16;
  const int qglobB = qgB * 16 + q16;
  const int ntilesA = (qgA >> 2) + 1;
  const int ntilesB = (qgB >> 2) + 1;

  __shared__ float ol[4][16][68];  // stride 68: 2-way bank aliasing only
  __shared__ float ll[4][16];

  const short* qf_h = qf + (size_t)bh * L_SEQ * 16;
  const short* kf_h = kf + (size_t)bh * L_SEQ * 16;
  const short* Vt_h = Vt + (size_t)bh * 64 * L_SEQ;
  const int b = bh >> 4, h = bh & 15;

  bf16x8 qfragA = {0, 0, 0, 0, 0, 0, 0, 0};
  bf16x8 qfragB = {0, 0, 0, 0, 0, 0, 0, 0};
  if (g < 2) {
    qfragA = *(const bf16x8*)(qf_h + (size_t)qglobA * 16 + g * 8);
    qfragB = *(const bf16x8*)(qf_h + (size_t)qglobB * 16 + g * 8);
  }

  f32x4 oA[4], oB[4];
#pragma unroll
  for (int dc = 0; dc < 4; ++dc) {
    oA[dc] = (f32x4){0.f, 0.f, 0.f, 0.f};
    oB[dc] = (f32x4){0.f, 0.f, 0.f, 0.f};
  }
  float lsumA = 0.f, lsumB = 0.f;

#pragma unroll 1
  for (int t = w; t < ntilesB; t += 4) {
    const int j0 = t << 6;

    // shared V for this tile: fully-coalesced 1 KB wave reads
    bf16x8 vf0[4], vf1[4];
#pragma unroll
    for (int dc = 0; dc < 4; ++dc)
      vf0[dc] = *(const bf16x8*)(Vt_h + ((size_t)((2 * t) * 4 + dc) << 9) +
                                 lane * 8);

    // shared K fragments for this tile
    bf16x8 kfr[4];
#pragma unroll
    for (int jt = 0; jt < 4; ++jt) {
      kfr[jt] = (bf16x8){0, 0, 0, 0, 0, 0, 0, 0};
      if (g < 2)
        kfr[jt] =
            *(const bf16x8*)(kf_h + (size_t)(j0 + jt * 16 + q16) * 16 + g * 8);
    }

#pragma unroll
    for (int dc = 0; dc < 4; ++dc)
      vf1[dc] = *(const bf16x8*)(Vt_h + ((size_t)((2 * t + 1) * 4 + dc) << 9) +
                                 lane * 8);

    // ================= q-group B (always active)
    {
      f32x4 s[4];
#pragma unroll
      for (int jt = 0; jt < 4; ++jt)
        s[jt] = __builtin_amdgcn_mfma_f32_16x16x32_bf16(
            kfr[jt], qfragB, (f32x4){0.f, 0.f, 0.f, 0.f}, 0, 0, 0);
      if (t == ntilesB - 1) {
#pragma unroll
        for (int jt = 0; jt < 4; ++jt)
#pragma unroll
          for (int r = 0; r < 4; ++r)
            if (j0 + jt * 16 + g * 4 + r > qglobB) s[jt][r] = -INFINITY;
      }
      float ex[4][4];
#pragma unroll
      for (int jt = 0; jt < 4; ++jt)
#pragma unroll
        for (int r = 0; r < 4; ++r) {
          ex[jt][r] = __expf(s[jt][r]);
          lsumB += ex[jt][r];
        }
#pragma unroll
      for (int c = 0; c < 2; ++c) {
        union {
          unsigned u[4];
          bf16x8 v;
        } pb;
#pragma unroll
        for (int hw = 0; hw < 2; ++hw) {
          asm("v_cvt_pk_bf16_f32 %0, %1, %2"
              : "=v"(pb.u[hw * 2 + 0])
              : "v"(ex[2 * c + hw][0]), "v"(ex[2 * c + hw][1]));
          asm("v_cvt_pk_bf16_f32 %0, %1, %2"
              : "=v"(pb.u[hw * 2 + 1])
              : "v"(ex[2 * c + hw][2]), "v"(ex[2 * c + hw][3]));
        }
        const bf16x8* vfc = c ? vf1 : vf0;
#pragma unroll
        for (int dc = 0; dc < 4; ++dc)
          oB[dc] = __builtin_amdgcn_mfma_f32_16x16x32_bf16(vfc[dc], pb.v,
                                                           oB[dc], 0, 0, 0);
      }
    }

    // ================= q-group A (prefix of B's j-range)
    if (t < ntilesA) {
      f32x4 s[4];
#pragma unroll
      for (int jt = 0; jt < 4; ++jt)
        s[jt] = __builtin_amdgcn_mfma_f32_16x16x32_bf16(
            kfr[jt], qfragA, (f32x4){0.f, 0.f, 0.f, 0.f}, 0, 0, 0);
      if (t == ntilesA - 1) {
#pragma unroll
        for (int jt = 0; jt < 4; ++jt)
#pragma unroll
          for (int r = 0; r < 4; ++r)
            if (j0 + jt * 16 + g * 4 + r > qglobA) s[jt][r] = -INFINITY;
      }
      float ex[4][4];
#pragma unroll
      for (int jt = 0; jt < 4; ++jt)
#pragma unroll
        for (int r = 0; r < 4; ++r) {
          ex[jt][r] = __expf(s[jt][r]);
          lsumA += ex[jt][r];
        }
#pragma unroll
      for (int c = 0; c < 2; ++c) {
        union {
          unsigned u[4];
          bf16x8 v;
        } pb;
#pragma unroll
        for (int hw = 0; hw < 2; ++hw) {
          asm("v_cvt_pk_bf16_f32 %0, %1, %2"
              : "=v"(pb.u[hw * 2 + 0])
              : "v"(ex[2 * c + hw][0]), "v"(ex[2 * c + hw][1]));
          asm("v_cvt_pk_bf16_f32 %0, %1, %2"
              : "=v"(pb.u[hw * 2 + 1])
              : "v"(ex[2 * c + hw][2]), "v"(ex[2 * c + hw][3]));
        }
        const bf16x8* vfc = c ? vf1 : vf0;
#pragma unroll
        for (int dc = 0; dc < 4; ++dc)
          oA[dc] = __builtin_amdgcn_mfma_f32_16x16x32_bf16(vfc[dc], pb.v,
                                                           oA[dc], 0, 0, 0);
      }
    }
  }

  // ---- combine q-group B
  lsumB += __shfl_xor(lsumB, 16);
  lsumB += __shfl_xor(lsumB, 32);
  if (g == 0) ll[w][q16] = lsumB;
#pragma unroll
  for (int dc = 0; dc < 4; ++dc)
    *(f32x4*)&ol[w][q16][dc * 16 + g * 4] = oB[dc];
  __syncthreads();
  {
    const float lt = (ll[0][q16] + ll[1][q16]) + (ll[2][q16] + ll[3][q16]);
    const float inv = 1.f / lt;
    const int d0 = w * 16 + g * 4;
    s16x4 pk;
#pragma unroll
    for (int r = 0; r < 4; ++r) {
      const float v = ((ol[0][q16][d0 + r] + ol[1][q16][d0 + r]) +
                       (ol[2][q16][d0 + r] + ol[3][q16][d0 + r]));
      pk[r] = (short)f2bf(v * inv);
    }
    short* orow = ao + ((size_t)(b * L_SEQ + qglobB)) * D_MODEL + h * 64;
    *(s16x4*)&orow[d0] = pk;
  }
  __syncthreads();

  // ---- combine q-group A
  lsumA += __shfl_xor(lsumA, 16);
  lsumA += __shfl_xor(lsumA, 32);
  if (g == 0) ll[w][q16] = lsumA;
#pragma unroll
  for (int dc = 0; dc < 4; ++dc)
    *(f32x4*)&ol[w][q16][dc * 16 + g * 4] = oA[dc];
  __syncthreads();
  {
    const float lt = (ll[0][q16] + ll[1][q16]) + (ll[2][q16] + ll[3][q16]);
    const float inv = 1.f / lt;
    const int d0 = w * 16 + g * 4;
    s16x4 pk;
#pragma unroll
    for (int r = 0; r < 4; ++r) {
      const float v = ((ol[0][q16][d0 + r] + ol[1][q16][d0 + r]) +
                       (ol[2][q16][d0 + r] + ol[3][q16][d0 + r]));
      pk[r] = (short)f2bf(v * inv);
    }
    short* orow = ao + ((size_t)(b * L_SEQ + qglobA)) * D_MODEL + h * 64;
    *(s16x4*)&orow[d0] = pk;
  }
}

// ---------------------------------------------------------------- layernorm (in place)
__global__ __launch_bounds__(256) void ln_kernel(float* __restrict__ io,
                                                 const float* __restrict__ gamma,
                                                 const float* __restrict__ beta) {
  const int row = blockIdx.x;
  float* p = io + (size_t)row * D_MODEL;
  const int tid = threadIdx.x;
  float4 x = ((const float4*)p)[tid];
  float s = x.x + x.y + x.z + x.w;
  float sq = x.x * x.x + x.y * x.y + x.z * x.z + x.w * x.w;
  s = wave_reduce_sum(s);
  sq = wave_reduce_sum(sq);
  __shared__ float ss[4], ssq[4];
  const int w = tid >> 6, lane = tid & 63;
  if (lane == 0) {
    ss[w] = s;
    ssq[w] = sq;
  }
  __syncthreads();
  s = ss[0] + ss[1] + ss[2] + ss[3];
  sq = ssq[0] + ssq[1] + ssq[2] + ssq[3];
  const float mean = s * (1.f / D_MODEL);
  const float var = sq * (1.f / D_MODEL) - mean * mean;
  const float rstd = rsqrtf(var + LN_EPS);
  const float4 g = ((const float4*)gamma)[tid];
  const float4 bt = ((const float4*)beta)[tid];
  float4 y;
  y.x = (x.x - mean) * rstd * g.x + bt.x;
  y.y = (x.y - mean) * rstd * g.y + bt.y;
  y.z = (x.z - mean) * rstd * g.z + bt.z;
  y.w = (x.w - mean) * rstd * g.w + bt.w;
  ((float4*)p)[tid] = y;
}

// ---------------------------------------------------------------- launch
extern "C" void kernel_launch(void* const* d_in, const int* in_sizes, int n_in,
                              void* d_out, int out_size, void* d_ws,
                              size_t ws_size, hipStream_t stream) {
  const float* x_real = (const float*)d_in[0];
  const float* x_imag = (const float*)d_in[1];
  const float* Wq = (const float*)d_in[2];
  const float* bq = (const float*)d_in[3];
  const float* Wk = (const float*)d_in[4];
  const float* bk = (const float*)d_in[5];
  const float* Wv = (const float*)d_in[6];
  const float* Wo = (const float*)d_in[7];
  const float* gamma = (const float*)d_in[8];
  const float* beta = (const float*)d_in[9];

  const size_t n_x = (size_t)B_SZ * L_SEQ * D_MODEL;        // 4M
  const size_t n_w = (size_t)D_MODEL * D_MODEL;             // 1M
  const size_t n_wp = (size_t)N_PHASE * D_MODEL;            // 128K
  const size_t n_qf = (size_t)B_SZ * N_HEADS * L_SEQ * 16;  // 1M

  short* xi_bf = (short*)d_ws;
  short* xr_bf = xi_bf + n_x;  // later reused as ao_bf
  short* Wq_bf = xr_bf + n_x;
  short* Wk_bf = Wq_bf + n_wp;
  short* Wv_bf = Wk_bf + n_wp;
  short* Wo_bf = Wv_bf + n_w;
  short* qf = Wo_bf + n_w;
  short* kf = qf + n_qf;
  short* Vt = kf + n_qf;  // 4M shorts
  short* ao_bf = xr_bf;   // alias: x_real bf16 dead after V GEMM

  float* outr = (float*)d_out;
  float* outi = outr + n_x;

  const dim3 blk(256);
  const int M = B_SZ * L_SEQ;  // 4096

  const int cvt_blocks = (NX4 + NWP4 + NW4 + 255) / 256;
  cvtall_kernel<<<dim3(cvt_blocks), blk, 0, stream>>>(
      x_real, x_imag, Wq, Wk, Wv, Wo, xr_bf, xi_bf, Wq_bf, Wk_bf, Wv_bf,
      Wo_bf, outi);

  qkv_kernel<<<dim3(M / 128, 20), blk, 0, stream>>>(
      xi_bf, xr_bf, Wq_bf, Wk_bf, Wv_bf, bq, bk, qf, kf, Vt);
  attn_mfma_kernel<<<dim3(B_SZ * N_HEADS, 64), blk, 0, stream>>>(qf, kf, Vt,
                                                                 ao_bf);
  ogemm_kernel<<<dim3(M / 128, D_MODEL / 64), blk, 0, stream>>>(
      ao_bf, Wo_bf, x_real, outr);
  ln_kernel<<<dim3(M), blk, 0, stream>>>(outr, gamma, beta);
}

// Round 18
// 89.328 us; speedup vs baseline: 1.2172x; 1.0073x over previous
//
#include <hip/hip_runtime.h>
#include <math.h>

#define D_MODEL 1024
#define N_HEADS 16
#define N_PHASE 128
#define HEAD_DIM 64
#define B_SZ 2
#define L_SEQ 2048
#define QK_SCALE 0.35355339059327373f   // 1/sqrt(8)
#define LOG2E 1.4426950408889634f
#define LN_EPS 1e-5f
#define POS_COEF 0.07195578415606394f   // ln(10000)/128
#define INV_2PI 0.15915494309189535f

typedef __attribute__((ext_vector_type(8))) short bf16x8;
typedef __attribute__((ext_vector_type(4))) short s16x4;
typedef __attribute__((ext_vector_type(4))) float f32x4;

// ---------------------------------------------------------------- helpers
__device__ __forceinline__ float wave_reduce_sum(float v) {
#pragma unroll
  for (int off = 32; off > 0; off >>= 1) v += __shfl_xor(v, off);
  return v;
}
// f32 -> bf16 (RNE)
__device__ __forceinline__ unsigned short f2bf(float x) {
  unsigned u = __float_as_uint(x);
  u += 0x7fffu + ((u >> 16) & 1u);
  return (unsigned short)(u >> 16);
}
__device__ __forceinline__ void gload16(const short* g, short* l) {
  __builtin_amdgcn_global_load_lds(
      (const __attribute__((address_space(1))) void*)g,
      (__attribute__((address_space(3))) void*)l, 16, 0, 0);
}
// raw 2^x (input already in log2 units; -inf -> 0)
__device__ __forceinline__ float exp2_raw(float x) {
  float r;
  asm("v_exp_f32 %0, %1" : "=v"(r) : "v"(x));
  return r;
}
// hw sin/cos with explicit range reduction (v_sin/v_cos take REVOLUTIONS,
// limited domain -> reduce to [-0.5, 0.5] rev with rndne first)
__device__ __forceinline__ void fast_sincos(float ang, float* s, float* c) {
  float rev = ang * INV_2PI;
  rev = rev - rintf(rev);
  *c = __builtin_amdgcn_cosf(rev);
  *s = __builtin_amdgcn_sinf(rev);
}

// ---------------------------------------------------------------- merged converts
#define NX4 ((B_SZ * L_SEQ * D_MODEL) / 4)
#define NWP4 ((N_PHASE * D_MODEL) / 4)
#define NW4 ((D_MODEL * D_MODEL) / 4)
__device__ __forceinline__ s16x4 cvt4(float4 v) {
  s16x4 o;
  o[0] = (short)f2bf(v.x);
  o[1] = (short)f2bf(v.y);
  o[2] = (short)f2bf(v.z);
  o[3] = (short)f2bf(v.w);
  return o;
}
__global__ __launch_bounds__(256) void cvtall_kernel(
    const float* __restrict__ x_real, const float* __restrict__ x_imag,
    const float* __restrict__ Wq, const float* __restrict__ Wk,
    const float* __restrict__ Wv, const float* __restrict__ Wo,
    short* __restrict__ xr_bf, short* __restrict__ xi_bf,
    short* __restrict__ Wq_bf, short* __restrict__ Wk_bf,
    short* __restrict__ Wv_bf, short* __restrict__ Wo_bf,
    float* __restrict__ outi) {
  const int i = blockIdx.x * 256 + threadIdx.x;
  if (i < NX4) {
    const float4 vi = ((const float4*)x_imag)[i];
    ((float4*)outi)[i] = vi;
    ((s16x4*)xi_bf)[i] = cvt4(vi);
    ((s16x4*)xr_bf)[i] = cvt4(((const float4*)x_real)[i]);
  } else if (i < NX4 + NWP4) {
    const int j = i - NX4;
    ((s16x4*)Wq_bf)[j] = cvt4(((const float4*)Wq)[j]);
    ((s16x4*)Wk_bf)[j] = cvt4(((const float4*)Wk)[j]);
  } else if (i < NX4 + NWP4 + NW4) {
    const int j = i - NX4 - NWP4;
    ((s16x4*)Wv_bf)[j] = cvt4(((const float4*)Wv)[j]);
    ((s16x4*)Wo_bf)[j] = cvt4(((const float4*)Wo)[j]);
  }
}

// ---------------------------------------------------------------- GEMM core
// 128x64 tile, BK=64 (2 barriers per 64-wide K step -> half the drains of
// BK=32). Staging: 8 rows x 8 chunks of 8 shorts per gload16; involution
// swizzle chunk ^= (row&7) on the GLOBAL source (gload_lds dest is linear);
// read side uses p = (kk*4+fc) ^ (fr&7) -> 2-way bank spread (free).
__device__ __forceinline__ void gemm_core(const short* __restrict__ A,
                                          const short* __restrict__ Bm, int K,
                                          int mBase, int nBase,
                                          f32x4 acc[4][2], short* As,
                                          short* Bs) {
  const int tid = threadIdx.x;
  const int wv = tid >> 6, ln = tid & 63;
  const int wr = wv >> 1, wc = wv & 1;
  const int fr = ln & 15, fc = ln >> 4;
  const int row8 = ln >> 3;              // 0..7 within an 8-row stripe
  const int cg = (ln & 7) ^ row8;        // swizzled global source chunk
  const short* ga = A + (size_t)(mBase + wv * 32 + row8) * K + cg * 8;
  const short* gb = Bm + (size_t)(nBase + wv * 16 + row8) * K + cg * 8;
  short* la = As + wv * 2048;            // 32 rows x 64 cols per wave
  short* lb = Bs + wv * 1024;            // 16 rows x 64 cols per wave
  const int swz = fr & 7;

  for (int k0 = 0; k0 < K; k0 += 64) {
    __syncthreads();
#pragma unroll
    for (int i = 0; i < 4; ++i)
      gload16(ga + k0 + (size_t)(8 * i) * K, la + i * 512);
#pragma unroll
    for (int i = 0; i < 2; ++i)
      gload16(gb + k0 + (size_t)(8 * i) * K, lb + i * 512);
    __syncthreads();

    bf16x8 af[2][4], bfr[2][2];
#pragma unroll
    for (int kk = 0; kk < 2; ++kk) {
      const int pc = ((kk * 4 + fc) ^ swz) * 8;
#pragma unroll
      for (int mi = 0; mi < 4; ++mi)
        af[kk][mi] =
            *(const bf16x8*)&As[(wr * 64 + mi * 16 + fr) * 64 + pc];
#pragma unroll
      for (int ni = 0; ni < 2; ++ni)
        bfr[kk][ni] =
            *(const bf16x8*)&Bs[(wc * 32 + ni * 16 + fr) * 64 + pc];
    }
#pragma unroll
    for (int kk = 0; kk < 2; ++kk)
#pragma unroll
      for (int mi = 0; mi < 4; ++mi)
#pragma unroll
        for (int ni = 0; ni < 2; ++ni)
          acc[mi][ni] = __builtin_amdgcn_mfma_f32_16x16x32_bf16(
              af[kk][mi], bfr[kk][ni], acc[mi][ni], 0, 0, 0);
  }
}

// ---------------------------------------------------------------- fused QKV projections
// grid (M/128, 20): y in [0,2) -> Q phase, [2,4) -> K phase, [4,20) -> V GEMM
__global__ __launch_bounds__(256) void qkv_kernel(
    const short* __restrict__ xi, const short* __restrict__ xr,
    const short* __restrict__ WqB, const short* __restrict__ WkB,
    const short* __restrict__ WvB, const float* __restrict__ bq,
    const float* __restrict__ bk, short* __restrict__ qf,
    short* __restrict__ kf, short* __restrict__ Vt) {
  __shared__ short As[128 * 64];
  __shared__ short Bs[64 * 64];
  const int y = blockIdx.y;
  const int mBase = blockIdx.x * 128;
  const short* A;
  const short* Bm;
  int nBase;
  if (y < 4) {
    A = xi;
    Bm = (y < 2) ? WqB : WkB;
    nBase = (y & 1) * 64;
  } else {
    A = xr;
    Bm = WvB;
    nBase = (y - 4) * 64;
  }

  f32x4 acc[4][2];
#pragma unroll
  for (int i = 0; i < 4; ++i)
#pragma unroll
    for (int j = 0; j < 2; ++j) acc[i][j] = (f32x4){0.f, 0.f, 0.f, 0.f};
  gemm_core(A, Bm, D_MODEL, mBase, nBase, acc, As, Bs);

  const int ln = threadIdx.x & 63, wv = threadIdx.x >> 6;
  const int wr = wv >> 1, wc = wv & 1;
  const int fr = ln & 15, fc = ln >> 4;

  if (y < 4) {
    const float* bias = (y < 2) ? bq : bk;
    short* Cs = (y < 2) ? qf : kf;
    // fold log2(e) into Q's scale so attention can use raw v_exp (2^x)
    const float fscale = (y < 2) ? (QK_SCALE * LOG2E) : 1.0f;
#pragma unroll
    for (int mi = 0; mi < 4; ++mi)
#pragma unroll
      for (int ni = 0; ni < 2; ++ni)
#pragma unroll
        for (int r = 0; r < 4; ++r) {
          const int m = mBase + wr * 64 + mi * 16 + fc * 4 + r;
          const int n = nBase + wc * 32 + ni * 16 + fr;
          const int b = m >> 11, l = m & (L_SEQ - 1);
          const float inv_freq = __expf(-(float)(n & ~1) * POS_COEF);
          const float ang = acc[mi][ni][r] + bias[n] + (float)l * inv_freq;
          float sv, cv;
          fast_sincos(ang, &sv, &cv);
          const int h = n >> 3, p = n & 7;
          const size_t base = ((size_t)((b << 4) + h) * L_SEQ + l) * 16;
          Cs[base + p] = (short)f2bf(cv * fscale);
          Cs[base + 8 + p] = (short)f2bf(sv * fscale);
        }
  } else {
    // Vt: PI-permuted j-rows (position [g1 g0 e2 e1 e0] holds row
    // [e2 g1 g0 e1 e0]) AND subtile-contiguous layout: each 16d x 32j
    // subtile is 1 KB contiguous, ordered [g][dlo][e] to match lane order,
    // so attention's V load is a fully-coalesced 1 KB wave read.
#pragma unroll
    for (int mi = 0; mi < 4; ++mi)
#pragma unroll
      for (int ni = 0; ni < 2; ++ni) {
        const int n = nBase + wc * 32 + ni * 16 + fr;
        const int m = mBase + wr * 64 + mi * 16 + fc * 4;
        const int b = m >> 11, l = m & (L_SEQ - 1);
        const int t = (l >> 2) & 7;
        const int tp = ((t << 1) & 6) | (t >> 2);
        const int lpos = (l & ~31) | (tp << 2);
        const int h = n >> 6, d = n & 63;
        const int jc = lpos >> 5, jlo = lpos & 31;
        const int gg = jlo >> 3, ee = jlo & 7;
        s16x4 pk;
#pragma unroll
        for (int r = 0; r < 4; ++r) pk[r] = (short)f2bf(acc[mi][ni][r]);
        const size_t off = (size_t)((b << 4) + h) * 64 * L_SEQ +
                           (size_t)(jc * 4 + (d >> 4)) * 512 + gg * 128 +
                           (d & 15) * 8 + ee;
        *(s16x4*)&Vt[off] = pk;
      }
  }
}

// ---------------------------------------------------------------- O GEMM (+residual)
__global__ __launch_bounds__(256) void ogemm_kernel(
    const short* __restrict__ A, const short* __restrict__ Bm,
    const float* __restrict__ resid, float* __restrict__ Cf) {
  __shared__ short As[128 * 64];
  __shared__ short Bs[64 * 64];
  const int mBase = blockIdx.x * 128, nBase = blockIdx.y * 64;

  f32x4 acc[4][2];
#pragma unroll
  for (int i = 0; i < 4; ++i)
#pragma unroll
    for (int j = 0; j < 2; ++j) acc[i][j] = (f32x4){0.f, 0.f, 0.f, 0.f};
  gemm_core(A, Bm, D_MODEL, mBase, nBase, acc, As, Bs);

  const int ln = threadIdx.x & 63, wv = threadIdx.x >> 6;
  const int wr = wv >> 1, wc = wv & 1;
  const int fr = ln & 15, fc = ln >> 4;
#pragma unroll
  for (int mi = 0; mi < 4; ++mi)
#pragma unroll
    for (int ni = 0; ni < 2; ++ni)
#pragma unroll
      for (int r = 0; r < 4; ++r) {
        const int m = mBase + wr * 64 + mi * 16 + fc * 4 + r;
        const int n = nBase + wc * 32 + ni * 16 + fr;
        const size_t idx = (size_t)m * D_MODEL + n;
        Cf[idx] = acc[mi][ni][r] + resid[idx];
      }
}

// ---------------------------------------------------------------- MFMA attention
// Paired flash-split: grid (B*H, 64); block owns q-groups qgA = y (short)
// and qgB = 127 - y (long); one t-loop serves both with K/V loaded once.
// Scores arrive pre-scaled by log2e -> raw v_exp_f32 (no per-element mul).
// s_setprio(1) around MFMA clusters (T5: +4-7% on barrier-free attn waves).
__global__ __launch_bounds__(256) void attn_mfma_kernel(
    const short* __restrict__ qf, const short* __restrict__ kf,
    const short* __restrict__ Vt, short* __restrict__ ao) {
  const int bh = blockIdx.x;
  const int qgA = (int)blockIdx.y;        // short extent
  const int qgB = 127 - (int)blockIdx.y;  // long extent
  const int tid = threadIdx.x;
  const int w = tid >> 6;
  const int lane = tid & 63;
  const int g = lane >> 4;
  const int q16 = lane & 15;
  const int qglobA = qgA * 16 + q16;
  const int qglobB = qgB * 16 + q16;
  const int ntilesA = (qgA >> 2) + 1;
  const int ntilesB = (qgB >> 2) + 1;

  __shared__ float ol[4][16][68];  // stride 68: 2-way bank aliasing only
  __shared__ float ll[4][16];

  const short* qf_h = qf + (size_t)bh * L_SEQ * 16;
  const short* kf_h = kf + (size_t)bh * L_SEQ * 16;
  const short* Vt_h = Vt + (size_t)bh * 64 * L_SEQ;
  const int b = bh >> 4, h = bh & 15;

  bf16x8 qfragA = {0, 0, 0, 0, 0, 0, 0, 0};
  bf16x8 qfragB = {0, 0, 0, 0, 0, 0, 0, 0};
  if (g < 2) {
    qfragA = *(const bf16x8*)(qf_h + (size_t)qglobA * 16 + g * 8);
    qfragB = *(const bf16x8*)(qf_h + (size_t)qglobB * 16 + g * 8);
  }

  f32x4 oA[4], oB[4];
#pragma unroll
  for (int dc = 0; dc < 4; ++dc) {
    oA[dc] = (f32x4){0.f, 0.f, 0.f, 0.f};
    oB[dc] = (f32x4){0.f, 0.f, 0.f, 0.f};
  }
  float lsumA = 0.f, lsumB = 0.f;

#pragma unroll 1
  for (int t = w; t < ntilesB; t += 4) {
    const int j0 = t << 6;

    // shared V for this tile: fully-coalesced 1 KB wave reads
    bf16x8 vf0[4], vf1[4];
#pragma unroll
    for (int dc = 0; dc < 4; ++dc)
      vf0[dc] = *(const bf16x8*)(Vt_h + ((size_t)((2 * t) * 4 + dc) << 9) +
                                 lane * 8);

    // shared K fragments for this tile
    bf16x8 kfr[4];
#pragma unroll
    for (int jt = 0; jt < 4; ++jt) {
      kfr[jt] = (bf16x8){0, 0, 0, 0, 0, 0, 0, 0};
      if (g < 2)
        kfr[jt] =
            *(const bf16x8*)(kf_h + (size_t)(j0 + jt * 16 + q16) * 16 + g * 8);
    }

#pragma unroll
    for (int dc = 0; dc < 4; ++dc)
      vf1[dc] = *(const bf16x8*)(Vt_h + ((size_t)((2 * t + 1) * 4 + dc) << 9) +
                                 lane * 8);

    // ================= q-group B (always active)
    {
      f32x4 s[4];
      __builtin_amdgcn_s_setprio(1);
#pragma unroll
      for (int jt = 0; jt < 4; ++jt)
        s[jt] = __builtin_amdgcn_mfma_f32_16x16x32_bf16(
            kfr[jt], qfragB, (f32x4){0.f, 0.f, 0.f, 0.f}, 0, 0, 0);
      __builtin_amdgcn_s_setprio(0);
      if (t == ntilesB - 1) {
#pragma unroll
        for (int jt = 0; jt < 4; ++jt)
#pragma unroll
          for (int r = 0; r < 4; ++r)
            if (j0 + jt * 16 + g * 4 + r > qglobB) s[jt][r] = -INFINITY;
      }
      float ex[4][4];
#pragma unroll
      for (int jt = 0; jt < 4; ++jt)
#pragma unroll
        for (int r = 0; r < 4; ++r) {
          ex[jt][r] = exp2_raw(s[jt][r]);
          lsumB += ex[jt][r];
        }
      __builtin_amdgcn_s_setprio(1);
#pragma unroll
      for (int c = 0; c < 2; ++c) {
        union {
          unsigned u[4];
          bf16x8 v;
        } pb;
#pragma unroll
        for (int hw = 0; hw < 2; ++hw) {
          asm("v_cvt_pk_bf16_f32 %0, %1, %2"
              : "=v"(pb.u[hw * 2 + 0])
              : "v"(ex[2 * c + hw][0]), "v"(ex[2 * c + hw][1]));
          asm("v_cvt_pk_bf16_f32 %0, %1, %2"
              : "=v"(pb.u[hw * 2 + 1])
              : "v"(ex[2 * c + hw][2]), "v"(ex[2 * c + hw][3]));
        }
        const bf16x8* vfc = c ? vf1 : vf0;
#pragma unroll
        for (int dc = 0; dc < 4; ++dc)
          oB[dc] = __builtin_amdgcn_mfma_f32_16x16x32_bf16(vfc[dc], pb.v,
                                                           oB[dc], 0, 0, 0);
      }
      __builtin_amdgcn_s_setprio(0);
    }

    // ================= q-group A (prefix of B's j-range)
    if (t < ntilesA) {
      f32x4 s[4];
      __builtin_amdgcn_s_setprio(1);
#pragma unroll
      for (int jt = 0; jt < 4; ++jt)
        s[jt] = __builtin_amdgcn_mfma_f32_16x16x32_bf16(
            kfr[jt], qfragA, (f32x4){0.f, 0.f, 0.f, 0.f}, 0, 0, 0);
      __builtin_amdgcn_s_setprio(0);
      if (t == ntilesA - 1) {
#pragma unroll
        for (int jt = 0; jt < 4; ++jt)
#pragma unroll
          for (int r = 0; r < 4; ++r)
            if (j0 + jt * 16 + g * 4 + r > qglobA) s[jt][r] = -INFINITY;
      }
      float ex[4][4];
#pragma unroll
      for (int jt = 0; jt < 4; ++jt)
#pragma unroll
        for (int r = 0; r < 4; ++r) {
          ex[jt][r] = exp2_raw(s[jt][r]);
          lsumA += ex[jt][r];
        }
      __builtin_amdgcn_s_setprio(1);
#pragma unroll
      for (int c = 0; c < 2; ++c) {
        union {
          unsigned u[4];
          bf16x8 v;
        } pb;
#pragma unroll
        for (int hw = 0; hw < 2; ++hw) {
          asm("v_cvt_pk_bf16_f32 %0, %1, %2"
              : "=v"(pb.u[hw * 2 + 0])
              : "v"(ex[2 * c + hw][0]), "v"(ex[2 * c + hw][1]));
          asm("v_cvt_pk_bf16_f32 %0, %1, %2"
              : "=v"(pb.u[hw * 2 + 1])
              : "v"(ex[2 * c + hw][2]), "v"(ex[2 * c + hw][3]));
        }
        const bf16x8* vfc = c ? vf1 : vf0;
#pragma unroll
        for (int dc = 0; dc < 4; ++dc)
          oA[dc] = __builtin_amdgcn_mfma_f32_16x16x32_bf16(vfc[dc], pb.v,
                                                           oA[dc], 0, 0, 0);
      }
      __builtin_amdgcn_s_setprio(0);
    }
  }

  // ---- combine q-group B
  lsumB += __shfl_xor(lsumB, 16);
  lsumB += __shfl_xor(lsumB, 32);
  if (g == 0) ll[w][q16] = lsumB;
#pragma unroll
  for (int dc = 0; dc < 4; ++dc)
    *(f32x4*)&ol[w][q16][dc * 16 + g * 4] = oB[dc];
  __syncthreads();
  {
    const float lt = (ll[0][q16] + ll[1][q16]) + (ll[2][q16] + ll[3][q16]);
    const float inv = 1.f / lt;
    const int d0 = w * 16 + g * 4;
    s16x4 pk;
#pragma unroll
    for (int r = 0; r < 4; ++r) {
      const float v = ((ol[0][q16][d0 + r] + ol[1][q16][d0 + r]) +
                       (ol[2][q16][d0 + r] + ol[3][q16][d0 + r]));
      pk[r] = (short)f2bf(v * inv);
    }
    short* orow = ao + ((size_t)(b * L_SEQ + qglobB)) * D_MODEL + h * 64;
    *(s16x4*)&orow[d0] = pk;
  }
  __syncthreads();

  // ---- combine q-group A
  lsumA += __shfl_xor(lsumA, 16);
  lsumA += __shfl_xor(lsumA, 32);
  if (g == 0) ll[w][q16] = lsumA;
#pragma unroll
  for (int dc = 0; dc < 4; ++dc)
    *(f32x4*)&ol[w][q16][dc * 16 + g * 4] = oA[dc];
  __syncthreads();
  {
    const float lt = (ll[0][q16] + ll[1][q16]) + (ll[2][q16] + ll[3][q16]);
    const float inv = 1.f / lt;
    const int d0 = w * 16 + g * 4;
    s16x4 pk;
#pragma unroll
    for (int r = 0; r < 4; ++r) {
      const float v = ((ol[0][q16][d0 + r] + ol[1][q16][d0 + r]) +
                       (ol[2][q16][d0 + r] + ol[3][q16][d0 + r]));
      pk[r] = (short)f2bf(v * inv);
    }
    short* orow = ao + ((size_t)(b * L_SEQ + qglobA)) * D_MODEL + h * 64;
    *(s16x4*)&orow[d0] = pk;
  }
}

// ---------------------------------------------------------------- layernorm (in place)
__global__ __launch_bounds__(256) void ln_kernel(float* __restrict__ io,
                                                 const float* __restrict__ gamma,
                                                 const float* __restrict__ beta) {
  const int row = blockIdx.x;
  float* p = io + (size_t)row * D_MODEL;
  const int tid = threadIdx.x;
  float4 x = ((const float4*)p)[tid];
  float s = x.x + x.y + x.z + x.w;
  float sq = x.x * x.x + x.y * x.y + x.z * x.z + x.w * x.w;
  s = wave_reduce_sum(s);
  sq = wave_reduce_sum(sq);
  __shared__ float ss[4], ssq[4];
  const int w = tid >> 6, lane = tid & 63;
  if (lane == 0) {
    ss[w] = s;
    ssq[w] = sq;
  }
  __syncthreads();
  s = ss[0] + ss[1] + ss[2] + ss[3];
  sq = ssq[0] + ssq[1] + ssq[2] + ssq[3];
  const float mean = s * (1.f / D_MODEL);
  const float var = sq * (1.f / D_MODEL) - mean * mean;
  const float rstd = rsqrtf(var + LN_EPS);
  const float4 g = ((const float4*)gamma)[tid];
  const float4 bt = ((const float4*)beta)[tid];
  float4 y;
  y.x = (x.x - mean) * rstd * g.x + bt.x;
  y.y = (x.y - mean) * rstd * g.y + bt.y;
  y.z = (x.z - mean) * rstd * g.z + bt.z;
  y.w = (x.w - mean) * rstd * g.w + bt.w;
  ((float4*)p)[tid] = y;
}

// ---------------------------------------------------------------- launch
extern "C" void kernel_launch(void* const* d_in, const int* in_sizes, int n_in,
                              void* d_out, int out_size, void* d_ws,
                              size_t ws_size, hipStream_t stream) {
  const float* x_real = (const float*)d_in[0];
  const float* x_imag = (const float*)d_in[1];
  const float* Wq = (const float*)d_in[2];
  const float* bq = (const float*)d_in[3];
  const float* Wk = (const float*)d_in[4];
  const float* bk = (const float*)d_in[5];
  const float* Wv = (const float*)d_in[6];
  const float* Wo = (const float*)d_in[7];
  const float* gamma = (const float*)d_in[8];
  const float* beta = (const float*)d_in[9];

  const size_t n_x = (size_t)B_SZ * L_SEQ * D_MODEL;        // 4M
  const size_t n_w = (size_t)D_MODEL * D_MODEL;             // 1M
  const size_t n_wp = (size_t)N_PHASE * D_MODEL;            // 128K
  const size_t n_qf = (size_t)B_SZ * N_HEADS * L_SEQ * 16;  // 1M

  short* xi_bf = (short*)d_ws;
  short* xr_bf = xi_bf + n_x;  // later reused as ao_bf
  short* Wq_bf = xr_bf + n_x;
  short* Wk_bf = Wq_bf + n_wp;
  short* Wv_bf = Wk_bf + n_wp;
  short* Wo_bf = Wv_bf + n_w;
  short* qf = Wo_bf + n_w;
  short* kf = qf + n_qf;
  short* Vt = kf + n_qf;  // 4M shorts
  short* ao_bf = xr_bf;   // alias: x_real bf16 dead after V GEMM

  float* outr = (float*)d_out;
  float* outi = outr + n_x;

  const dim3 blk(256);
  const int M = B_SZ * L_SEQ;  // 4096

  const int cvt_blocks = (NX4 + NWP4 + NW4 + 255) / 256;
  cvtall_kernel<<<dim3(cvt_blocks), blk, 0, stream>>>(
      x_real, x_imag, Wq, Wk, Wv, Wo, xr_bf, xi_bf, Wq_bf, Wk_bf, Wv_bf,
      Wo_bf, outi);

  qkv_kernel<<<dim3(M / 128, 20), blk, 0, stream>>>(
      xi_bf, xr_bf, Wq_bf, Wk_bf, Wv_bf, bq, bk, qf, kf, Vt);
  attn_mfma_kernel<<<dim3(B_SZ * N_HEADS, 64), blk, 0, stream>>>(qf, kf, Vt,
                                                                 ao_bf);
  ogemm_kernel<<<dim3(M / 128, D_MODEL / 64), blk, 0, stream>>>(
      ao_bf, Wo_bf, x_real, outr);
  ln_kernel<<<dim3(M), blk, 0, stream>>>(outr, gamma, beta);
}